// Round 3
// baseline (418.599 us; speedup 1.0000x reference)
//
#include <hip/hip_runtime.h>
#include <stdint.h>

#define NB 32
#define SEQ 128
#define EMB 128
#define NSTEP 127
#define NS 512

__device__ __forceinline__ float ftanh(float x){ float e=__expf(2.f*x); return 1.f-2.f/(e+1.f); }
__device__ __forceinline__ float fsig(float x){ return 1.f/(1.f+__expf(-x)); }
__device__ __forceinline__ float4 ld4(const float* p){ return *(const float4*)p; }

// ---------------------------------------------------------------------------
// Streamed-WT GEMM: out[r,e] = bias[e] + sum_k X[r,k] * WT[k,e]
// X in LDS [R][XS]; WT global row-major [K][NEtot] (pre-transposed).
// Threads = 32 e-threads (4 e each) x R row-threads (1 row each, rt=tid>>5).
// Works at 128 thr (4 rows) or 256 thr (8 rows).
// NAMED register double groups only — any VGPR array with non-constant index
// is demoted to scratch (prior session: 256 VGPR + 554 MB scratch traffic).
// ---------------------------------------------------------------------------
#define FMA4(acc, xv, a0, a1, a2, a3) \
  acc.x = fmaf(xv.x, a0.x, fmaf(xv.y, a1.x, fmaf(xv.z, a2.x, fmaf(xv.w, a3.x, acc.x)))); \
  acc.y = fmaf(xv.x, a0.y, fmaf(xv.y, a1.y, fmaf(xv.z, a2.y, fmaf(xv.w, a3.y, acc.y)))); \
  acc.z = fmaf(xv.x, a0.z, fmaf(xv.y, a1.z, fmaf(xv.z, a2.z, fmaf(xv.w, a3.z, acc.z)))); \
  acc.w = fmaf(xv.x, a0.w, fmaf(xv.y, a1.w, fmaf(xv.z, a2.w, fmaf(xv.w, a3.w, acc.w))));

template<int K, int XS>
__device__ __forceinline__ void gemm8(const float* __restrict__ WT, int NEtot,
                                      const float* Xl, const float* __restrict__ bias,
                                      float* outb)
{
  const int tid = threadIdx.x;
  const int et = tid & 31;
  const int rt = tid >> 5;
  const float* wp = WT + et*4;
  const float* xr = Xl + rt*XS;
  constexpr int G = K/4;
  float4 acc = {0.f,0.f,0.f,0.f};
  float4 w0 = ld4(wp);
  float4 w1 = ld4(wp + NEtot);
  float4 w2 = ld4(wp + 2*NEtot);
  float4 w3 = ld4(wp + 3*NEtot);
  const float* wq = wp + (size_t)4*NEtot;
  float4 m0 = ld4(wq);
  float4 m1 = ld4(wq + NEtot);
  float4 m2 = ld4(wq + 2*NEtot);
  float4 m3 = ld4(wq + 3*NEtot);
  #pragma unroll 2
  for (int g = 0; g + 2 < G; g += 2) {
    const float* wa = wp + (size_t)(4*(g+2))*NEtot;
    float4 n0 = ld4(wa);
    float4 n1 = ld4(wa + NEtot);
    float4 n2 = ld4(wa + 2*NEtot);
    float4 n3 = ld4(wa + 3*NEtot);
    float4 xa = ld4(xr + 4*g);
    FMA4(acc, xa, w0, w1, w2, w3);
    w0=n0; w1=n1; w2=n2; w3=n3;
    const float* wb = wp + (size_t)(4*(g+3))*NEtot;
    float4 o0 = ld4(wb);
    float4 o1 = ld4(wb + NEtot);
    float4 o2 = ld4(wb + 2*NEtot);
    float4 o3 = ld4(wb + 3*NEtot);
    float4 xb = ld4(xr + 4*(g+1));
    FMA4(acc, xb, m0, m1, m2, m3);
    m0=o0; m1=o1; m2=o2; m3=o3;
  }
  {
    float4 xa = ld4(xr + 4*(G-2));
    FMA4(acc, xa, w0, w1, w2, w3);
    float4 xb = ld4(xr + 4*(G-1));
    FMA4(acc, xb, m0, m1, m2, m3);
  }
  float4 bb = ld4(bias + et*4);
  acc.x+=bb.x; acc.y+=bb.y; acc.z+=bb.z; acc.w+=bb.w;
  *(float4*)(outb + rt*132 + et*4) = acc;
}

// ---------------------------------------------------------------------------
// k_T: transpose weights into ws, BIH = b_ih+b_hh, c_pad, zero G1/Pmaxi
// ---------------------------------------------------------------------------
__global__ __launch_bounds__(256) void k_T(
    const float* __restrict__ W_agg, const float* __restrict__ W_last,
    const float* __restrict__ W_query, const float* __restrict__ W_ih,
    const float* __restrict__ b_ih, const float* __restrict__ b_hh,
    const float* __restrict__ b_query, const float* __restrict__ w_W,
    float* __restrict__ WT012, float* __restrict__ WLT, float* __restrict__ WQT,
    float* __restrict__ WIHT, float* __restrict__ BIH, float* __restrict__ CPAD,
    float* __restrict__ G1, int* __restrict__ Pmaxi)
{
  const int gid = blockIdx.x*256 + threadIdx.x;
  const int gsz = gridDim.x*256;
  for (int i = gid; i < 49152; i += gsz) {
    int j = i >> 14, rem = i & 16383, k = rem >> 7, e = rem & 127;
    WT012[i] = W_agg[j*16384 + e*128 + k];
  }
  for (int i = gid; i < 16384; i += gsz) {
    int k = i >> 7, e = i & 127;
    WLT[i] = W_last[e*128 + k];
    WQT[i] = W_query[e*128 + k];
  }
  for (int i = gid; i < 131072; i += gsz) {
    int k = i >> 9, e = i & 511;
    WIHT[i] = W_ih[e*256 + k];
  }
  for (int i = gid; i < 65536; i += gsz) G1[i] = 0.f;
  if (gid < 512) BIH[gid] = b_ih[gid] + b_hh[gid];
  if (gid < 128) Pmaxi[gid] = 0;
  if (blockIdx.x == 0) {
    __shared__ float red[256];
    float v = (threadIdx.x < 128) ? ftanh(b_query[threadIdx.x]) * w_W[128 + threadIdx.x] : 0.f;
    red[threadIdx.x] = v; __syncthreads();
    #pragma unroll
    for (int s = 128; s > 0; s >>= 1) {
      if (threadIdx.x < s) red[threadIdx.x] += red[threadIdx.x + s];
      __syncthreads();
    }
    if (threadIdx.x == 0) CPAD[0] = red[0];
  }
}

// ---------------------------------------------------------------------------
// k_pre: 128-thr blocks, 4 rows each. Blocks 0..127: E1 (4 s-rows).
// Blocks 128..1407: 4 of 5120 (s,j) level-2 pairs, atomicAdd into G1.
// ---------------------------------------------------------------------------
__global__ __launch_bounds__(128) void k_pre(
    const int* __restrict__ s_neighbors, const int* __restrict__ q_neighbors,
    const float* __restrict__ emb_q, const float* __restrict__ emb_s,
    const float* __restrict__ WT012, const float* __restrict__ b_agg,
    float* __restrict__ E1, float* __restrict__ G1)
{
  __shared__ float XA[4*132];
  __shared__ float XB[4*132];
  __shared__ int idx[40];
  __shared__ int n3[16];
  const int tid = threadIdx.x;
  const int blk = blockIdx.x;
  if (blk < 128) {
    const int s0 = blk*4;
    if (tid < 40) idx[tid] = s_neighbors[s0*10 + tid];
    __syncthreads();
    {
      int r = tid >> 5, e4 = (tid & 31) << 2;
      float4 a = ld4(emb_s + (size_t)(s0+r)*128 + e4);
      float sx=0,sy=0,sz=0,sw=0;
      #pragma unroll
      for (int jj = 0; jj < 10; ++jj) {
        float4 q = ld4(emb_q + (size_t)idx[r*10+jj]*128 + e4);
        sx+=q.x; sy+=q.y; sz+=q.z; sw+=q.w;
      }
      float4 o; o.x=a.x+0.1f*sx; o.y=a.y+0.1f*sy; o.z=a.z+0.1f*sz; o.w=a.w+0.1f*sw;
      *(float4*)(XA + r*132 + e4) = o;
    }
    __syncthreads();
    gemm8<128,132>(WT012 + 16384, 128, XA, b_agg + 128, XB);
    __syncthreads();
    for (int f = tid; f < 512; f += 128) {
      int r = f >> 7, e = f & 127;
      E1[(size_t)(s0+r)*128 + e] = ftanh(XB[r*132 + e]);
    }
  } else {
    const int p0 = (blk-128)*4;
    if (tid < 4) idx[tid] = s_neighbors[p0 + tid];
    __syncthreads();
    if (tid < 16) n3[tid] = q_neighbors[(size_t)idx[tid>>2]*4 + (tid&3)];
    __syncthreads();
    {
      int r = tid >> 5, e4 = (tid & 31) << 2;
      float4 a = ld4(emb_q + (size_t)idx[r]*128 + e4);
      float sx=0,sy=0,sz=0,sw=0;
      #pragma unroll
      for (int k = 0; k < 4; ++k) {
        float4 q = ld4(emb_s + (size_t)n3[r*4+k]*128 + e4);
        sx+=q.x; sy+=q.y; sz+=q.z; sw+=q.w;
      }
      float4 o; o.x=a.x+0.25f*sx; o.y=a.y+0.25f*sy; o.z=a.z+0.25f*sz; o.w=a.w+0.25f*sw;
      *(float4*)(XA + r*132 + e4) = o;
    }
    __syncthreads();
    gemm8<128,132>(WT012 + 32768, 128, XA, b_agg + 256, XB);
    __syncthreads();
    for (int f = tid; f < 512; f += 128) {
      int r = f >> 7, e = f & 127;
      atomicAdd(&G1[(size_t)((p0+r)/10)*128 + e], ftanh(XB[r*132 + e]));
    }
  }
}

// k_pre2: E2[s] = tanh((0.1*G1[s] + E1[s]) @ W1.T + b1)  (128 blocks x 4 rows)
__global__ __launch_bounds__(128) void k_pre2(
    const float* __restrict__ E1, const float* __restrict__ G1,
    const float* __restrict__ WT012, const float* __restrict__ b_agg,
    float* __restrict__ E2)
{
  __shared__ float XA[4*132];
  __shared__ float XB[4*132];
  const int tid = threadIdx.x;
  const int s0 = blockIdx.x*4;
  for (int f = tid; f < 512; f += 128) {
    int r = f >> 7, e = f & 127;
    XA[r*132 + e] = 0.1f*G1[(size_t)(s0+r)*128 + e] + E1[(size_t)(s0+r)*128 + e];
  }
  __syncthreads();
  gemm8<128,132>(WT012 + 16384, 128, XA, b_agg + 128, XB);
  __syncthreads();
  for (int f = tid; f < 512; f += 128) {
    int r = f >> 7, e = f & 127;
    E2[(size_t)(s0+r)*128 + e] = ftanh(XB[r*132 + e]);
  }
}

// ---------------------------------------------------------------------------
// k_chain: 508 blocks x 256 thr x 8 (b,t)-rows: aggregation + LSTM h + Cq,
// plus fused k_match (per-wave, 2 rows/wave, __shfl broadcast — no barriers).
// NR=1 (8 rt groups x 1 row): LDS 25KB -> 2 blocks/CU = 2 waves/SIMD.
// Same per-SIMD VALU wall as round-2's NR=2, but 2-deep TLP hides the L2
// latency of the streamed weight panels (round-2 had 1 wave/SIMD = no TLP).
// ---------------------------------------------------------------------------
__global__ __launch_bounds__(256) void k_chain(
    const int* __restrict__ question, const int* __restrict__ response,
    const int* __restrict__ maskp, const int* __restrict__ q_neighbors,
    const int* __restrict__ s_neighbors,
    const float* __restrict__ emb_q, const float* __restrict__ emb_s,
    const float* __restrict__ emb_r,
    const float* __restrict__ WT012, const float* __restrict__ WLT,
    const float* __restrict__ WQT, const float* __restrict__ WIHT,
    const float* __restrict__ BIH,
    const float* __restrict__ b_agg, const float* __restrict__ b_last,
    const float* __restrict__ b_query, const float* __restrict__ w_W,
    const float* __restrict__ E1, const float* __restrict__ E2,
    float* __restrict__ Hfull, float* __restrict__ Cq,
    int* __restrict__ nsel, unsigned long long* __restrict__ mwords,
    int* __restrict__ Pmaxi)
{
  __shared__ float XA[8*132];
  __shared__ float XB[8*132];
  __shared__ float M1[8*132];
  __shared__ float M2[8*132];
  __shared__ float XC[8*264];
  __shared__ int qts[8], rts[8], mts[8], n1s[32];

  const int tid = threadIdx.x;
  const int blk = blockIdx.x;

  if (tid < 8) {
    int rid = blk*8 + tid;
    int b = rid / 127, t = rid - b*127;
    qts[tid] = question[b*SEQ + t];
    rts[tid] = response[b*SEQ + t];
    mts[tid] = maskp[b*SEQ + t];
  }
  __syncthreads();
  if (tid < 32) n1s[tid] = q_neighbors[(size_t)qts[tid>>2]*4 + (tid&3)];
  __syncthreads();
  // XA = emb_q[qt] + 0.25*sum emb_s[n1]; M1 = 0.25*sum E1[n1]; M2 = 0.25*sum E2[n1]
  {
    const int e4 = (tid & 31) << 2;
    const int rr = tid >> 5;   // 0..7, exactly one row per thread-group
    const int* nn = n1s + rr*4;
    float4 a = ld4(emb_q + (size_t)qts[rr]*128 + e4);
    float s1x=0,s1y=0,s1z=0,s1w=0, s2x=0,s2y=0,s2z=0,s2w=0, s3x=0,s3y=0,s3z=0,s3w=0;
    #pragma unroll
    for (int i = 0; i < 4; ++i) {
      float4 q1 = ld4(emb_s + (size_t)nn[i]*128 + e4);
      float4 q2 = ld4(E1 + (size_t)nn[i]*128 + e4);
      float4 q3 = ld4(E2 + (size_t)nn[i]*128 + e4);
      s1x+=q1.x; s1y+=q1.y; s1z+=q1.z; s1w+=q1.w;
      s2x+=q2.x; s2y+=q2.y; s2z+=q2.z; s2w+=q2.w;
      s3x+=q3.x; s3y+=q3.y; s3z+=q3.z; s3w+=q3.w;
    }
    float4 o; o.x=a.x+0.25f*s1x; o.y=a.y+0.25f*s1y; o.z=a.z+0.25f*s1z; o.w=a.w+0.25f*s1w;
    *(float4*)(XA + rr*132 + e4) = o;
    float4 p; p.x=0.25f*s2x; p.y=0.25f*s2y; p.z=0.25f*s2z; p.w=0.25f*s2w;
    *(float4*)(M1 + rr*132 + e4) = p;
    float4 u; u.x=0.25f*s3x; u.y=0.25f*s3y; u.z=0.25f*s3z; u.w=0.25f*s3w;
    *(float4*)(M2 + rr*132 + e4) = u;
  }
  // 3-stage aggregation chain
  __syncthreads();
  gemm8<128,132>(WT012, 128, XA, b_agg, XB);     // e0_1 pre-act
  __syncthreads();
  for (int f = tid; f < 1056; f += 256) XB[f] = M1[f] + ftanh(XB[f]);
  __syncthreads();
  gemm8<128,132>(WT012, 128, XB, b_agg, XA);     // e0_2 pre-act
  __syncthreads();
  for (int f = tid; f < 1056; f += 256) XA[f] = M2[f] + ftanh(XA[f]);
  __syncthreads();
  gemm8<128,132>(WT012, 128, XA, b_agg, XB);     // e0_3 pre-act
  __syncthreads();
  for (int f = tid; f < 1056; f += 256) XB[f] = ftanh(XB[f]);
  __syncthreads();
  gemm8<128,132>(WLT, 128, XB, b_last, XA);      // agg pre-act
  __syncthreads();
  for (int f = tid; f < 1024; f += 256) {
    int r = f >> 7, e = f & 127;
    float agg = ftanh(XA[r*132 + e]);
    XC[r*264 + e] = (mts[r] == 1) ? agg : emb_q[(size_t)qts[r]*128 + e];
    XC[r*264 + 128 + e] = emb_r[rts[r]*128 + e];
  }
  __syncthreads();
  // LSTM gates gi/gg/go (gf unused by the reference's h formula)
  gemm8<256,264>(WIHT,       512, XC, BIH,       XA);
  gemm8<256,264>(WIHT + 256, 512, XC, BIH + 256, XB);
  gemm8<256,264>(WIHT + 384, 512, XC, BIH + 384, M1);
  __syncthreads();
  for (int f = tid; f < 1024; f += 256) {
    int r = f >> 7, e = f & 127;
    float gi = XA[r*132 + e], gg = XB[r*132 + e], go = M1[r*132 + e];
    float h = fsig(go) * ftanh(fsig(gi) * ftanh(gg));
    XC[r*264 + e] = h;
    Hfull[(size_t)(blk*8 + r)*128 + e] = h;
  }
  __syncthreads();
  gemm8<128,264>(WQT, 128, XC, b_query, XA);     // c pre-act
  __syncthreads();
  {
    const int et = tid & 31, rr = tid >> 5;
    float4 wv = ld4(w_W + 128 + et*4);
    float4 o = ld4(XA + rr*132 + et*4);
    float s = ftanh(o.x)*wv.x + ftanh(o.y)*wv.y + ftanh(o.z)*wv.z + ftanh(o.w)*wv.w;
    #pragma unroll
    for (int off = 16; off > 0; off >>= 1) s += __shfl_down(s, off);
    if (et == 0) Cq[blk*8 + rr] = s;
  }
  // ---- fused k_match: wave w handles rows w and w+4 ----
  {
    const int wv = tid >> 6;      // wave 0..3
    const int ln = tid & 63;      // lane 0..63
    for (int rr = wv; rr < 8; rr += 4) {
      int rid = blk*8 + rr;
      int b = rid / 127, t = rid - b*127;
      int q_next = question[b*SEQ + t + 1];
      int qrv = 0;
      if (ln < 40)
        qrv = s_neighbors[(size_t)q_neighbors[(size_t)q_next*4 + ln/10]*10 + ln%10];
      int q0 = question[b*SEQ + ln];
      int q1 = question[b*SEQ + 64 + ln];
      bool p0 = false, p1 = false;
      #pragma unroll 8
      for (int i = 0; i < 40; ++i) {
        int qv = __shfl(qrv, i);
        p0 |= (q0 == qv); p1 |= (q1 == qv);
      }
      p0 &= (ln < t);
      p1 &= (64 + ln < t);
      unsigned long long w0 = __ballot(p0);
      unsigned long long w1 = __ballot(p1);
      if (ln == 0) {
        size_t bt = (size_t)b*NSTEP + t;
        mwords[bt*2 + 0] = w0;
        mwords[bt*2 + 1] = w1;
        int ns = __popcll(w0) + __popcll(w1);
        nsel[bt] = ns;
        atomicMax(&Pmaxi[t], ns);
      }
    }
  }
}

__device__ __forceinline__ float wredsum(float v) {
  #pragma unroll
  for (int o = 32; o > 0; o >>= 1) v += __shfl_down(v, o);
  return v;
}
__device__ __forceinline__ float wredmax(float v) {
  #pragma unroll
  for (int o = 32; o > 0; o >>= 1) v = fmaxf(v, __shfl_down(v, o));
  return v;
}

// ---------------------------------------------------------------------------
// k_attn: collapsed attention (a[q] cancels across the softmax), y -> out
// ---------------------------------------------------------------------------
__global__ __launch_bounds__(128) void k_attn(
    const int* __restrict__ question, const float* __restrict__ qs_table,
    const float* __restrict__ emb_q, const float* __restrict__ emb_s,
    const float* __restrict__ CPAD,
    const float* __restrict__ Hfull, const float* __restrict__ Cq,
    const int* __restrict__ nsel, const unsigned long long* __restrict__ mwords,
    const int* __restrict__ Pmaxi, float* __restrict__ out)
{
  __shared__ float us[128];
  __shared__ int cols[8];
  __shared__ int cnt;
  __shared__ float smx[2];
  __shared__ float s3[2][3];
  const int tid = threadIdx.x;
  const int wid = tid >> 6;
  const int bid = blockIdx.x;
  const int b = bid / NSTEP, t = bid % NSTEP;
  const size_t bt = (size_t)b*NSTEP + t;
  const int q_next = question[b*SEQ + t + 1];

  if (tid == 0) cnt = 0;
  __syncthreads();
  {
    float4 v = ld4(qs_table + (size_t)q_next*NS + tid*4);
    if (v.x > 0.f) { int p = atomicAdd(&cnt, 1); if (p < 8) cols[p] = tid*4; }
    if (v.y > 0.f) { int p = atomicAdd(&cnt, 1); if (p < 8) cols[p] = tid*4+1; }
    if (v.z > 0.f) { int p = atomicAdd(&cnt, 1); if (p < 8) cols[p] = tid*4+2; }
    if (v.w > 0.f) { int p = atomicAdd(&cnt, 1); if (p < 8) cols[p] = tid*4+3; }
  }
  __syncthreads();
  const int nc = min(cnt, 4);
  {
    float ue = emb_q[(size_t)q_next*EMB + tid];
    for (int i = 0; i < nc; ++i) ue += emb_s[(size_t)cols[i]*EMB + tid];
    us[tid] = ue;
  }
  const float c_pad = CPAD[0];
  const float P = (float)(Pmaxi[t] - nsel[bt]);

  const unsigned long long w0 = mwords[bt*2 + 0];
  const unsigned long long w1 = mwords[bt*2 + 1];
  const bool matched = (tid < 64) ? ((w0 >> tid) & 1ull)
                                  : ((w1 >> (tid - 64)) & 1ull);
  const float c_cur = Cq[bt];
  float Cp = matched ? ((tid == 0) ? c_pad : Cq[(size_t)b*NSTEP + tid]) : -3.0e38f;
  float mh = wredmax(Cp);
  if ((tid & 63) == 0) smx[wid] = mh;
  __syncthreads();   // also publishes us[]
  float M = fmaxf(fmaxf(smx[0], smx[1]), fmaxf(c_cur, c_pad));
  float wgt = matched ? __expf(Cp - M) : 0.f;
  float dotp = 0.f;
  if (matched && tid >= 1) {  // p=0 history row is zeros
    const float* hp = Hfull + ((size_t)b*NSTEP + tid)*EMB;
    float s = 0.f;
    #pragma unroll 8
    for (int e = 0; e < 128; e += 4) {
      float4 h4 = ld4(hp + e);
      s = fmaf(us[e],h4.x, fmaf(us[e+1],h4.y, fmaf(us[e+2],h4.z, fmaf(us[e+3],h4.w, s))));
    }
    dotp = s;
  }
  float gcp = us[tid] * Hfull[bt*EMB + tid];
  float a0 = wredsum(wgt);
  float a1 = wredsum(wgt * dotp);
  float a2 = wredsum(gcp);
  if ((tid & 63) == 0) { s3[wid][0] = a0; s3[wid][1] = a1; s3[wid][2] = a2; }
  __syncthreads();
  if (tid == 0) {
    float Sexp = s3[0][0] + s3[1][0];
    float Snum = s3[0][1] + s3[1][1];
    float gc   = s3[0][2] + s3[1][2];
    float Ec = __expf(c_cur - M), Ep = __expf(c_pad - M);
    float D = Sexp + Ec + P * Ep;
    float numt = Snum + Ec * gc;
    out[b*SEQ + t + 1] = fsig(numt / D);
    if (t == 0) out[b*SEQ] = 0.5f;
  }
}

extern "C" void kernel_launch(void* const* d_in, const int* in_sizes, int n_in,
                              void* d_out, int out_size, void* d_ws, size_t ws_size,
                              hipStream_t stream) {
  const int* question    = (const int*)d_in[0];
  const int* response    = (const int*)d_in[1];
  const int* maskp       = (const int*)d_in[2];
  const int* q_neighbors = (const int*)d_in[3];
  const int* s_neighbors = (const int*)d_in[4];
  const float* qs_table  = (const float*)d_in[5];
  const float* emb_q     = (const float*)d_in[6];
  const float* emb_s     = (const float*)d_in[7];
  const float* emb_r     = (const float*)d_in[8];
  const float* W_ih      = (const float*)d_in[9];
  const float* b_ih      = (const float*)d_in[10];
  const float* b_hh      = (const float*)d_in[11];
  const float* W_agg     = (const float*)d_in[12];
  const float* b_agg     = (const float*)d_in[13];
  const float* W_last    = (const float*)d_in[14];
  const float* b_last    = (const float*)d_in[15];
  const float* W_query   = (const float*)d_in[16];
  const float* b_query   = (const float*)d_in[17];
  // d_in[18] W_key, d_in[19] b_key, d_in[21] b_W: no effect (a[q] cancels)
  const float* w_W       = (const float*)d_in[20];
  float* out = (float*)d_out;

  float* ws = (float*)d_ws;
  float* WT012 = ws;                    // 49152
  float* WLT   = ws + 49152;            // 16384
  float* WQT   = ws + 65536;            // 16384
  float* WIHT  = ws + 81920;            // 131072  [256][512]
  float* BIH   = ws + 212992;           // 512
  float* CPAD  = ws + 213504;           // 16
  float* E1    = ws + 213520;           // 65536
  float* G1    = ws + 279056;           // 65536
  float* E2    = ws + 344592;           // 65536
  float* Hfull = ws + 410128;           // 520192
  float* Cq    = ws + 930320;           // 4064
  int*   Pmaxi = (int*)(ws + 934384);   // 128
  int*   nselp = (int*)(ws + 934512);   // 4064
  unsigned long long* mwords =
      (unsigned long long*)(((uintptr_t)(ws + 938576) + 15) & ~(uintptr_t)15);

  k_T<<<dim3(512), dim3(256), 0, stream>>>(
      W_agg, W_last, W_query, W_ih, b_ih, b_hh, b_query, w_W,
      WT012, WLT, WQT, WIHT, BIH, CPAD, G1, Pmaxi);
  k_pre<<<dim3(1408), dim3(128), 0, stream>>>(
      s_neighbors, q_neighbors, emb_q, emb_s, WT012, b_agg, E1, G1);
  k_pre2<<<dim3(128), dim3(128), 0, stream>>>(E1, G1, WT012, b_agg, E2);
  k_chain<<<dim3(508), dim3(256), 0, stream>>>(
      question, response, maskp, q_neighbors, s_neighbors, emb_q, emb_s, emb_r,
      WT012, WLT, WQT, WIHT, BIH, b_agg, b_last, b_query, w_W,
      E1, E2, Hfull, Cq, nselp, mwords, Pmaxi);
  k_attn<<<dim3(NB*NSTEP), dim3(128), 0, stream>>>(
      question, qs_table, emb_q, emb_s, CPAD, Hfull, Cq,
      nselp, mwords, Pmaxi, out);
}

// Round 4
// 392.666 us; speedup vs baseline: 1.0660x; 1.0660x over previous
//
#include <hip/hip_runtime.h>
#include <stdint.h>

#define NB 32
#define SEQ 128
#define EMB 128
#define NSTEP 127
#define NS 512

__device__ __forceinline__ float ftanh(float x){ float e=__expf(2.f*x); return 1.f-2.f/(e+1.f); }
__device__ __forceinline__ float fsig(float x){ return 1.f/(1.f+__expf(-x)); }
__device__ __forceinline__ float4 ld4(const float* p){ return *(const float4*)p; }

// ---------------------------------------------------------------------------
// Streamed-WT GEMM: out[r,e] = bias[e] + sum_k X[r,k] * WT[k,e]
// X in LDS [R][XS]; WT global row-major [K][NEtot] (pre-transposed).
// NAMED register double groups only — any VGPR array with non-constant index
// is demoted to scratch (prior session: 256 VGPR + 554 MB scratch traffic).
// ---------------------------------------------------------------------------
#define FMA4(acc, xv, a0, a1, a2, a3) \
  acc.x = fmaf(xv.x, a0.x, fmaf(xv.y, a1.x, fmaf(xv.z, a2.x, fmaf(xv.w, a3.x, acc.x)))); \
  acc.y = fmaf(xv.x, a0.y, fmaf(xv.y, a1.y, fmaf(xv.z, a2.y, fmaf(xv.w, a3.y, acc.y)))); \
  acc.z = fmaf(xv.x, a0.z, fmaf(xv.y, a1.z, fmaf(xv.z, a2.z, fmaf(xv.w, a3.z, acc.z)))); \
  acc.w = fmaf(xv.x, a0.w, fmaf(xv.y, a1.w, fmaf(xv.z, a2.w, fmaf(xv.w, a3.w, acc.w))));

// gemm8: 128-thr blocks, 1 row per thread (32 et x 4 rt). Used by k_pre/k_pre2.
template<int K, int XS>
__device__ __forceinline__ void gemm8(const float* __restrict__ WT, int NEtot,
                                      const float* Xl, const float* __restrict__ bias,
                                      float* outb)
{
  const int tid = threadIdx.x;
  const int et = tid & 31;
  const int rt = tid >> 5;
  const float* wp = WT + et*4;
  const float* xr = Xl + rt*XS;
  constexpr int G = K/4;
  float4 acc = {0.f,0.f,0.f,0.f};
  float4 w0 = ld4(wp);
  float4 w1 = ld4(wp + NEtot);
  float4 w2 = ld4(wp + 2*NEtot);
  float4 w3 = ld4(wp + 3*NEtot);
  const float* wq = wp + (size_t)4*NEtot;
  float4 m0 = ld4(wq);
  float4 m1 = ld4(wq + NEtot);
  float4 m2 = ld4(wq + 2*NEtot);
  float4 m3 = ld4(wq + 3*NEtot);
  #pragma unroll 2
  for (int g = 0; g + 2 < G; g += 2) {
    const float* wa = wp + (size_t)(4*(g+2))*NEtot;
    float4 n0 = ld4(wa);
    float4 n1 = ld4(wa + NEtot);
    float4 n2 = ld4(wa + 2*NEtot);
    float4 n3 = ld4(wa + 3*NEtot);
    float4 xa = ld4(xr + 4*g);
    FMA4(acc, xa, w0, w1, w2, w3);
    w0=n0; w1=n1; w2=n2; w3=n3;
    const float* wb = wp + (size_t)(4*(g+3))*NEtot;
    float4 o0 = ld4(wb);
    float4 o1 = ld4(wb + NEtot);
    float4 o2 = ld4(wb + 2*NEtot);
    float4 o3 = ld4(wb + 3*NEtot);
    float4 xb = ld4(xr + 4*(g+1));
    FMA4(acc, xb, m0, m1, m2, m3);
    m0=o0; m1=o1; m2=o2; m3=o3;
  }
  {
    float4 xa = ld4(xr + 4*(G-2));
    FMA4(acc, xa, w0, w1, w2, w3);
    float4 xb = ld4(xr + 4*(G-1));
    FMA4(acc, xb, m0, m1, m2, m3);
  }
  float4 bb = ld4(bias + et*4);
  acc.x+=bb.x; acc.y+=bb.y; acc.z+=bb.z; acc.w+=bb.w;
  *(float4*)(outb + rt*132 + et*4) = acc;
}

// ---------------------------------------------------------------------------
// gemmKS: 512-thr blocks, K-SPLIT. et=tid&31 (4 cols, float4 loads),
// kt=(tid>>5)&1 (half of K each), rg=tid>>6 (8 groups x NR=2 rows = 16 rows).
// vs round-2 gemm2/256thr: SAME chip-wide FMA count, SAME VMEM instruction
// count (2x threads x half K each), SAME unique weight bytes per block —
// but 8 waves/block -> 2 waves/SIMD (round 2 had 1): pure latency-hiding.
// kt=0 adds bias and writes outb; kt=1 writes raw partial to partb.
// Caller must sum outb+partb after the following __syncthreads.
// ---------------------------------------------------------------------------
template<int K, int XS>
__device__ __forceinline__ void gemmKS(const float* __restrict__ WT, int NEtot,
                                       const float* Xl, const float* __restrict__ bias,
                                       float* outb, float* partb)
{
  const int tid = threadIdx.x;
  const int et = tid & 31;
  const int kt = (tid >> 5) & 1;
  const int rg = tid >> 6;                 // 0..7
  constexpr int KH = K/2;
  constexpr int G  = KH/4;
  const float* wp = WT + (size_t)kt*KH*NEtot + et*4;
  const float* xr = Xl + (size_t)(rg*2)*XS + kt*KH;
  float4 a0 = {0.f,0.f,0.f,0.f};
  float4 a1 = {0.f,0.f,0.f,0.f};
  float4 w0 = ld4(wp);
  float4 w1 = ld4(wp + NEtot);
  float4 w2 = ld4(wp + 2*NEtot);
  float4 w3 = ld4(wp + 3*NEtot);
  const float* wq = wp + (size_t)4*NEtot;
  float4 m0 = ld4(wq);
  float4 m1 = ld4(wq + NEtot);
  float4 m2 = ld4(wq + 2*NEtot);
  float4 m3 = ld4(wq + 3*NEtot);
  #pragma unroll 2
  for (int g = 0; g + 2 < G; g += 2) {
    const float* wa = wp + (size_t)(4*(g+2))*NEtot;
    float4 n0 = ld4(wa);
    float4 n1 = ld4(wa + NEtot);
    float4 n2 = ld4(wa + 2*NEtot);
    float4 n3 = ld4(wa + 3*NEtot);
    float4 xa0 = ld4(xr + 4*g);
    float4 xa1 = ld4(xr + XS + 4*g);
    FMA4(a0, xa0, w0, w1, w2, w3);
    FMA4(a1, xa1, w0, w1, w2, w3);
    w0=n0; w1=n1; w2=n2; w3=n3;
    const float* wb = wp + (size_t)(4*(g+3))*NEtot;
    float4 o0 = ld4(wb);
    float4 o1 = ld4(wb + NEtot);
    float4 o2 = ld4(wb + 2*NEtot);
    float4 o3 = ld4(wb + 3*NEtot);
    float4 xb0 = ld4(xr + 4*(g+1));
    float4 xb1 = ld4(xr + XS + 4*(g+1));
    FMA4(a0, xb0, m0, m1, m2, m3);
    FMA4(a1, xb1, m0, m1, m2, m3);
    m0=o0; m1=o1; m2=o2; m3=o3;
  }
  {
    float4 xa0 = ld4(xr + 4*(G-2));
    float4 xa1 = ld4(xr + XS + 4*(G-2));
    FMA4(a0, xa0, w0, w1, w2, w3);
    FMA4(a1, xa1, w0, w1, w2, w3);
    float4 xb0 = ld4(xr + 4*(G-1));
    float4 xb1 = ld4(xr + XS + 4*(G-1));
    FMA4(a0, xb0, m0, m1, m2, m3);
    FMA4(a1, xb1, m0, m1, m2, m3);
  }
  float* dst;
  if (kt == 0) {
    float4 bb = ld4(bias + et*4);
    a0.x+=bb.x; a0.y+=bb.y; a0.z+=bb.z; a0.w+=bb.w;
    a1.x+=bb.x; a1.y+=bb.y; a1.z+=bb.z; a1.w+=bb.w;
    dst = outb;
  } else {
    dst = partb;
  }
  float* ob = dst + (size_t)(rg*2)*132 + et*4;
  *(float4*)(ob)       = a0;
  *(float4*)(ob + 132) = a1;
}

// ---------------------------------------------------------------------------
// k_T: transpose weights into ws, BIH = b_ih+b_hh, c_pad, zero G1/Pmaxi
// ---------------------------------------------------------------------------
__global__ __launch_bounds__(256) void k_T(
    const float* __restrict__ W_agg, const float* __restrict__ W_last,
    const float* __restrict__ W_query, const float* __restrict__ W_ih,
    const float* __restrict__ b_ih, const float* __restrict__ b_hh,
    const float* __restrict__ b_query, const float* __restrict__ w_W,
    float* __restrict__ WT012, float* __restrict__ WLT, float* __restrict__ WQT,
    float* __restrict__ WIHT, float* __restrict__ BIH, float* __restrict__ CPAD,
    float* __restrict__ G1, int* __restrict__ Pmaxi)
{
  const int gid = blockIdx.x*256 + threadIdx.x;
  const int gsz = gridDim.x*256;
  for (int i = gid; i < 49152; i += gsz) {
    int j = i >> 14, rem = i & 16383, k = rem >> 7, e = rem & 127;
    WT012[i] = W_agg[j*16384 + e*128 + k];
  }
  for (int i = gid; i < 16384; i += gsz) {
    int k = i >> 7, e = i & 127;
    WLT[i] = W_last[e*128 + k];
    WQT[i] = W_query[e*128 + k];
  }
  for (int i = gid; i < 131072; i += gsz) {
    int k = i >> 9, e = i & 511;
    WIHT[i] = W_ih[e*256 + k];
  }
  for (int i = gid; i < 65536; i += gsz) G1[i] = 0.f;
  if (gid < 512) BIH[gid] = b_ih[gid] + b_hh[gid];
  if (gid < 128) Pmaxi[gid] = 0;
  if (blockIdx.x == 0) {
    __shared__ float red[256];
    float v = (threadIdx.x < 128) ? ftanh(b_query[threadIdx.x]) * w_W[128 + threadIdx.x] : 0.f;
    red[threadIdx.x] = v; __syncthreads();
    #pragma unroll
    for (int s = 128; s > 0; s >>= 1) {
      if (threadIdx.x < s) red[threadIdx.x] += red[threadIdx.x + s];
      __syncthreads();
    }
    if (threadIdx.x == 0) CPAD[0] = red[0];
  }
}

// ---------------------------------------------------------------------------
// k_pre: 128-thr blocks, 4 rows each. Blocks 0..127: E1 (4 s-rows).
// Blocks 128..1407: 4 of 5120 (s,j) level-2 pairs, atomicAdd into G1.
// ---------------------------------------------------------------------------
__global__ __launch_bounds__(128) void k_pre(
    const int* __restrict__ s_neighbors, const int* __restrict__ q_neighbors,
    const float* __restrict__ emb_q, const float* __restrict__ emb_s,
    const float* __restrict__ WT012, const float* __restrict__ b_agg,
    float* __restrict__ E1, float* __restrict__ G1)
{
  __shared__ float XA[4*132];
  __shared__ float XB[4*132];
  __shared__ int idx[40];
  __shared__ int n3[16];
  const int tid = threadIdx.x;
  const int blk = blockIdx.x;
  if (blk < 128) {
    const int s0 = blk*4;
    if (tid < 40) idx[tid] = s_neighbors[s0*10 + tid];
    __syncthreads();
    {
      int r = tid >> 5, e4 = (tid & 31) << 2;
      float4 a = ld4(emb_s + (size_t)(s0+r)*128 + e4);
      float sx=0,sy=0,sz=0,sw=0;
      #pragma unroll
      for (int jj = 0; jj < 10; ++jj) {
        float4 q = ld4(emb_q + (size_t)idx[r*10+jj]*128 + e4);
        sx+=q.x; sy+=q.y; sz+=q.z; sw+=q.w;
      }
      float4 o; o.x=a.x+0.1f*sx; o.y=a.y+0.1f*sy; o.z=a.z+0.1f*sz; o.w=a.w+0.1f*sw;
      *(float4*)(XA + r*132 + e4) = o;
    }
    __syncthreads();
    gemm8<128,132>(WT012 + 16384, 128, XA, b_agg + 128, XB);
    __syncthreads();
    for (int f = tid; f < 512; f += 128) {
      int r = f >> 7, e = f & 127;
      E1[(size_t)(s0+r)*128 + e] = ftanh(XB[r*132 + e]);
    }
  } else {
    const int p0 = (blk-128)*4;
    if (tid < 4) idx[tid] = s_neighbors[p0 + tid];
    __syncthreads();
    if (tid < 16) n3[tid] = q_neighbors[(size_t)idx[tid>>2]*4 + (tid&3)];
    __syncthreads();
    {
      int r = tid >> 5, e4 = (tid & 31) << 2;
      float4 a = ld4(emb_q + (size_t)idx[r]*128 + e4);
      float sx=0,sy=0,sz=0,sw=0;
      #pragma unroll
      for (int k = 0; k < 4; ++k) {
        float4 q = ld4(emb_s + (size_t)n3[r*4+k]*128 + e4);
        sx+=q.x; sy+=q.y; sz+=q.z; sw+=q.w;
      }
      float4 o; o.x=a.x+0.25f*sx; o.y=a.y+0.25f*sy; o.z=a.z+0.25f*sz; o.w=a.w+0.25f*sw;
      *(float4*)(XA + r*132 + e4) = o;
    }
    __syncthreads();
    gemm8<128,132>(WT012 + 32768, 128, XA, b_agg + 256, XB);
    __syncthreads();
    for (int f = tid; f < 512; f += 128) {
      int r = f >> 7, e = f & 127;
      atomicAdd(&G1[(size_t)((p0+r)/10)*128 + e], ftanh(XB[r*132 + e]));
    }
  }
}

// k_pre2: E2[s] = tanh((0.1*G1[s] + E1[s]) @ W1.T + b1)  (128 blocks x 4 rows)
__global__ __launch_bounds__(128) void k_pre2(
    const float* __restrict__ E1, const float* __restrict__ G1,
    const float* __restrict__ WT012, const float* __restrict__ b_agg,
    float* __restrict__ E2)
{
  __shared__ float XA[4*132];
  __shared__ float XB[4*132];
  const int tid = threadIdx.x;
  const int s0 = blockIdx.x*4;
  for (int f = tid; f < 512; f += 128) {
    int r = f >> 7, e = f & 127;
    XA[r*132 + e] = 0.1f*G1[(size_t)(s0+r)*128 + e] + E1[(size_t)(s0+r)*128 + e];
  }
  __syncthreads();
  gemm8<128,132>(WT012 + 16384, 128, XA, b_agg + 128, XB);
  __syncthreads();
  for (int f = tid; f < 512; f += 128) {
    int r = f >> 7, e = f & 127;
    E2[(size_t)(s0+r)*128 + e] = ftanh(XB[r*132 + e]);
  }
}

// ---------------------------------------------------------------------------
// k_chain: 254 blocks x 512 thr x 16 (b,t)-rows, K-split gemms.
// Same shape/traffic as the round-2 best (254 blocks, 16 rows, 179MB L2,
// same VMEM instruction count) but 8 waves/block = 2 waves/SIMD for latency
// hiding. LDS 57.8KB. Fused k_match at the tail (8 waves x 2 rows).
// ---------------------------------------------------------------------------
__global__ __launch_bounds__(512) void k_chain(
    const int* __restrict__ question, const int* __restrict__ response,
    const int* __restrict__ maskp, const int* __restrict__ q_neighbors,
    const int* __restrict__ s_neighbors,
    const float* __restrict__ emb_q, const float* __restrict__ emb_s,
    const float* __restrict__ emb_r,
    const float* __restrict__ WT012, const float* __restrict__ WLT,
    const float* __restrict__ WQT, const float* __restrict__ WIHT,
    const float* __restrict__ BIH,
    const float* __restrict__ b_agg, const float* __restrict__ b_last,
    const float* __restrict__ b_query, const float* __restrict__ w_W,
    const float* __restrict__ E1, const float* __restrict__ E2,
    float* __restrict__ Hfull, float* __restrict__ Cq,
    int* __restrict__ nsel, unsigned long long* __restrict__ mwords,
    int* __restrict__ Pmaxi)
{
  __shared__ float XA[16*132];
  __shared__ float XB[16*132];
  __shared__ float M1[16*132];
  __shared__ float M2[16*132];
  __shared__ float PB[16*132];   // K-split partial
  __shared__ float XC[16*264];
  __shared__ int qts[16], rts[16], mts[16], n1s[64];

  const int tid = threadIdx.x;
  const int blk = blockIdx.x;

  if (tid < 16) {
    int rid = blk*16 + tid;
    int b = rid / 127, t = rid - b*127;
    qts[tid] = question[b*SEQ + t];
    rts[tid] = response[b*SEQ + t];
    mts[tid] = maskp[b*SEQ + t];
  }
  __syncthreads();
  if (tid < 64) n1s[tid] = q_neighbors[(size_t)qts[tid>>2]*4 + (tid&3)];
  __syncthreads();
  // XA = emb_q[qt] + 0.25*sum emb_s[n1]; M1 = 0.25*sum E1[n1]; M2 = 0.25*sum E2[n1]
  // 512 thr = 32 e-lanes x 16 rows exactly.
  {
    const int e4 = (tid & 31) << 2;
    const int rr = tid >> 5;   // 0..15
    const int* nn = n1s + rr*4;
    float4 a = ld4(emb_q + (size_t)qts[rr]*128 + e4);
    float s1x=0,s1y=0,s1z=0,s1w=0, s2x=0,s2y=0,s2z=0,s2w=0, s3x=0,s3y=0,s3z=0,s3w=0;
    #pragma unroll
    for (int i = 0; i < 4; ++i) {
      float4 q1 = ld4(emb_s + (size_t)nn[i]*128 + e4);
      float4 q2 = ld4(E1 + (size_t)nn[i]*128 + e4);
      float4 q3 = ld4(E2 + (size_t)nn[i]*128 + e4);
      s1x+=q1.x; s1y+=q1.y; s1z+=q1.z; s1w+=q1.w;
      s2x+=q2.x; s2y+=q2.y; s2z+=q2.z; s2w+=q2.w;
      s3x+=q3.x; s3y+=q3.y; s3z+=q3.z; s3w+=q3.w;
    }
    float4 o; o.x=a.x+0.25f*s1x; o.y=a.y+0.25f*s1y; o.z=a.z+0.25f*s1z; o.w=a.w+0.25f*s1w;
    *(float4*)(XA + rr*132 + e4) = o;
    float4 p; p.x=0.25f*s2x; p.y=0.25f*s2y; p.z=0.25f*s2z; p.w=0.25f*s2w;
    *(float4*)(M1 + rr*132 + e4) = p;
    float4 u; u.x=0.25f*s3x; u.y=0.25f*s3y; u.z=0.25f*s3z; u.w=0.25f*s3w;
    *(float4*)(M2 + rr*132 + e4) = u;
  }
  // 3-stage aggregation chain (each act-loop also merges the K-split partial)
  __syncthreads();
  gemmKS<128,132>(WT012, 128, XA, b_agg, XB, PB);     // e0_1 pre-act
  __syncthreads();
  for (int f = tid; f < 2048; f += 512) {
    int i = (f >> 7)*132 + (f & 127);
    XB[i] = M1[i] + ftanh(XB[i] + PB[i]);
  }
  __syncthreads();
  gemmKS<128,132>(WT012, 128, XB, b_agg, XA, PB);     // e0_2 pre-act
  __syncthreads();
  for (int f = tid; f < 2048; f += 512) {
    int i = (f >> 7)*132 + (f & 127);
    XA[i] = M2[i] + ftanh(XA[i] + PB[i]);
  }
  __syncthreads();
  gemmKS<128,132>(WT012, 128, XA, b_agg, XB, PB);     // e0_3 pre-act
  __syncthreads();
  for (int f = tid; f < 2048; f += 512) {
    int i = (f >> 7)*132 + (f & 127);
    XB[i] = ftanh(XB[i] + PB[i]);
  }
  __syncthreads();
  gemmKS<128,132>(WLT, 128, XB, b_last, XA, PB);      // agg pre-act
  __syncthreads();
  for (int f = tid; f < 2048; f += 512) {
    int r = f >> 7, e = f & 127, i = r*132 + e;
    float agg = ftanh(XA[i] + PB[i]);
    XC[r*264 + e] = (mts[r] == 1) ? agg : emb_q[(size_t)qts[r]*128 + e];
    XC[r*264 + 128 + e] = emb_r[rts[r]*128 + e];
  }
  __syncthreads();
  // LSTM gates gi/gg/go (gf unused by the reference's h formula).
  // PB is reused per gate -> merge gi/gg into their buffers between gemms.
  gemmKS<256,264>(WIHT,       512, XC, BIH,       XA, PB);
  __syncthreads();
  for (int f = tid; f < 2048; f += 512) {
    int i = (f >> 7)*132 + (f & 127);
    XA[i] += PB[i];
  }
  __syncthreads();
  gemmKS<256,264>(WIHT + 256, 512, XC, BIH + 256, XB, PB);
  __syncthreads();
  for (int f = tid; f < 2048; f += 512) {
    int i = (f >> 7)*132 + (f & 127);
    XB[i] += PB[i];
  }
  __syncthreads();
  gemmKS<256,264>(WIHT + 384, 512, XC, BIH + 384, M1, PB);
  __syncthreads();
  for (int f = tid; f < 2048; f += 512) {
    int r = f >> 7, e = f & 127, i = r*132 + e;
    float gi = XA[i], gg = XB[i], go = M1[i] + PB[i];
    float h = fsig(go) * ftanh(fsig(gi) * ftanh(gg));
    XC[r*264 + e] = h;
    Hfull[(size_t)(blk*16 + r)*128 + e] = h;
  }
  __syncthreads();
  gemmKS<128,264>(WQT, 128, XC, b_query, XA, PB);     // c pre-act
  __syncthreads();
  {
    const int et = tid & 31, rr = tid >> 5;   // 16 rows exactly
    float4 wv = ld4(w_W + 128 + et*4);
    float4 o = ld4(XA + rr*132 + et*4);
    float4 p = ld4(PB + rr*132 + et*4);
    float s = ftanh(o.x+p.x)*wv.x + ftanh(o.y+p.y)*wv.y
            + ftanh(o.z+p.z)*wv.z + ftanh(o.w+p.w)*wv.w;
    #pragma unroll
    for (int off = 16; off > 0; off >>= 1) s += __shfl_down(s, off);
    if (et == 0) Cq[blk*16 + rr] = s;
  }
  // ---- fused k_match: wave w handles rows w and w+8 ----
  {
    const int wv = tid >> 6;      // wave 0..7
    const int ln = tid & 63;      // lane 0..63
    for (int rr = wv; rr < 16; rr += 8) {
      int rid = blk*16 + rr;
      int b = rid / 127, t = rid - b*127;
      int q_next = question[b*SEQ + t + 1];
      int qrv = 0;
      if (ln < 40)
        qrv = s_neighbors[(size_t)q_neighbors[(size_t)q_next*4 + ln/10]*10 + ln%10];
      int q0 = question[b*SEQ + ln];
      int q1 = question[b*SEQ + 64 + ln];
      bool p0 = false, p1 = false;
      #pragma unroll 8
      for (int i = 0; i < 40; ++i) {
        int qv = __shfl(qrv, i);
        p0 |= (q0 == qv); p1 |= (q1 == qv);
      }
      p0 &= (ln < t);
      p1 &= (64 + ln < t);
      unsigned long long w0 = __ballot(p0);
      unsigned long long w1 = __ballot(p1);
      if (ln == 0) {
        size_t bt = (size_t)b*NSTEP + t;
        mwords[bt*2 + 0] = w0;
        mwords[bt*2 + 1] = w1;
        int ns = __popcll(w0) + __popcll(w1);
        nsel[bt] = ns;
        atomicMax(&Pmaxi[t], ns);
      }
    }
  }
}

__device__ __forceinline__ float wredsum(float v) {
  #pragma unroll
  for (int o = 32; o > 0; o >>= 1) v += __shfl_down(v, o);
  return v;
}
__device__ __forceinline__ float wredmax(float v) {
  #pragma unroll
  for (int o = 32; o > 0; o >>= 1) v = fmaxf(v, __shfl_down(v, o));
  return v;
}

// ---------------------------------------------------------------------------
// k_attn: collapsed attention (a[q] cancels across the softmax), y -> out
// ---------------------------------------------------------------------------
__global__ __launch_bounds__(128) void k_attn(
    const int* __restrict__ question, const float* __restrict__ qs_table,
    const float* __restrict__ emb_q, const float* __restrict__ emb_s,
    const float* __restrict__ CPAD,
    const float* __restrict__ Hfull, const float* __restrict__ Cq,
    const int* __restrict__ nsel, const unsigned long long* __restrict__ mwords,
    const int* __restrict__ Pmaxi, float* __restrict__ out)
{
  __shared__ float us[128];
  __shared__ int cols[8];
  __shared__ int cnt;
  __shared__ float smx[2];
  __shared__ float s3[2][3];
  const int tid = threadIdx.x;
  const int wid = tid >> 6;
  const int bid = blockIdx.x;
  const int b = bid / NSTEP, t = bid % NSTEP;
  const size_t bt = (size_t)b*NSTEP + t;
  const int q_next = question[b*SEQ + t + 1];

  if (tid == 0) cnt = 0;
  __syncthreads();
  {
    float4 v = ld4(qs_table + (size_t)q_next*NS + tid*4);
    if (v.x > 0.f) { int p = atomicAdd(&cnt, 1); if (p < 8) cols[p] = tid*4; }
    if (v.y > 0.f) { int p = atomicAdd(&cnt, 1); if (p < 8) cols[p] = tid*4+1; }
    if (v.z > 0.f) { int p = atomicAdd(&cnt, 1); if (p < 8) cols[p] = tid*4+2; }
    if (v.w > 0.f) { int p = atomicAdd(&cnt, 1); if (p < 8) cols[p] = tid*4+3; }
  }
  __syncthreads();
  const int nc = min(cnt, 4);
  {
    float ue = emb_q[(size_t)q_next*EMB + tid];
    for (int i = 0; i < nc; ++i) ue += emb_s[(size_t)cols[i]*EMB + tid];
    us[tid] = ue;
  }
  const float c_pad = CPAD[0];
  const float P = (float)(Pmaxi[t] - nsel[bt]);

  const unsigned long long w0 = mwords[bt*2 + 0];
  const unsigned long long w1 = mwords[bt*2 + 1];
  const bool matched = (tid < 64) ? ((w0 >> tid) & 1ull)
                                  : ((w1 >> (tid - 64)) & 1ull);
  const float c_cur = Cq[bt];
  float Cp = matched ? ((tid == 0) ? c_pad : Cq[(size_t)b*NSTEP + tid]) : -3.0e38f;
  float mh = wredmax(Cp);
  if ((tid & 63) == 0) smx[wid] = mh;
  __syncthreads();   // also publishes us[]
  float M = fmaxf(fmaxf(smx[0], smx[1]), fmaxf(c_cur, c_pad));
  float wgt = matched ? __expf(Cp - M) : 0.f;
  float dotp = 0.f;
  if (matched && tid >= 1) {  // p=0 history row is zeros
    const float* hp = Hfull + ((size_t)b*NSTEP + tid)*EMB;
    float s = 0.f;
    #pragma unroll 8
    for (int e = 0; e < 128; e += 4) {
      float4 h4 = ld4(hp + e);
      s = fmaf(us[e],h4.x, fmaf(us[e+1],h4.y, fmaf(us[e+2],h4.z, fmaf(us[e+3],h4.w, s))));
    }
    dotp = s;
  }
  float gcp = us[tid] * Hfull[bt*EMB + tid];
  float a0 = wredsum(wgt);
  float a1 = wredsum(wgt * dotp);
  float a2 = wredsum(gcp);
  if ((tid & 63) == 0) { s3[wid][0] = a0; s3[wid][1] = a1; s3[wid][2] = a2; }
  __syncthreads();
  if (tid == 0) {
    float Sexp = s3[0][0] + s3[1][0];
    float Snum = s3[0][1] + s3[1][1];
    float gc   = s3[0][2] + s3[1][2];
    float Ec = __expf(c_cur - M), Ep = __expf(c_pad - M);
    float D = Sexp + Ec + P * Ep;
    float numt = Snum + Ec * gc;
    out[b*SEQ + t + 1] = fsig(numt / D);
    if (t == 0) out[b*SEQ] = 0.5f;
  }
}

extern "C" void kernel_launch(void* const* d_in, const int* in_sizes, int n_in,
                              void* d_out, int out_size, void* d_ws, size_t ws_size,
                              hipStream_t stream) {
  const int* question    = (const int*)d_in[0];
  const int* response    = (const int*)d_in[1];
  const int* maskp       = (const int*)d_in[2];
  const int* q_neighbors = (const int*)d_in[3];
  const int* s_neighbors = (const int*)d_in[4];
  const float* qs_table  = (const float*)d_in[5];
  const float* emb_q     = (const float*)d_in[6];
  const float* emb_s     = (const float*)d_in[7];
  const float* emb_r     = (const float*)d_in[8];
  const float* W_ih      = (const float*)d_in[9];
  const float* b_ih      = (const float*)d_in[10];
  const float* b_hh      = (const float*)d_in[11];
  const float* W_agg     = (const float*)d_in[12];
  const float* b_agg     = (const float*)d_in[13];
  const float* W_last    = (const float*)d_in[14];
  const float* b_last    = (const float*)d_in[15];
  const float* W_query   = (const float*)d_in[16];
  const float* b_query   = (const float*)d_in[17];
  // d_in[18] W_key, d_in[19] b_key, d_in[21] b_W: no effect (a[q] cancels)
  const float* w_W       = (const float*)d_in[20];
  float* out = (float*)d_out;

  float* ws = (float*)d_ws;
  float* WT012 = ws;                    // 49152
  float* WLT   = ws + 49152;            // 16384
  float* WQT   = ws + 65536;            // 16384
  float* WIHT  = ws + 81920;            // 131072  [256][512]
  float* BIH   = ws + 212992;           // 512
  float* CPAD  = ws + 213504;           // 16
  float* E1    = ws + 213520;           // 65536
  float* G1    = ws + 279056;           // 65536
  float* E2    = ws + 344592;           // 65536
  float* Hfull = ws + 410128;           // 520192
  float* Cq    = ws + 930320;           // 4064
  int*   Pmaxi = (int*)(ws + 934384);   // 128
  int*   nselp = (int*)(ws + 934512);   // 4064
  unsigned long long* mwords =
      (unsigned long long*)(((uintptr_t)(ws + 938576) + 15) & ~(uintptr_t)15);

  k_T<<<dim3(512), dim3(256), 0, stream>>>(
      W_agg, W_last, W_query, W_ih, b_ih, b_hh, b_query, w_W,
      WT012, WLT, WQT, WIHT, BIH, CPAD, G1, Pmaxi);
  k_pre<<<dim3(1408), dim3(128), 0, stream>>>(
      s_neighbors, q_neighbors, emb_q, emb_s, WT012, b_agg, E1, G1);
  k_pre2<<<dim3(128), dim3(128), 0, stream>>>(E1, G1, WT012, b_agg, E2);
  k_chain<<<dim3(254), dim3(512), 0, stream>>>(
      question, response, maskp, q_neighbors, s_neighbors, emb_q, emb_s, emb_r,
      WT012, WLT, WQT, WIHT, BIH, b_agg, b_last, b_query, w_W,
      E1, E2, Hfull, Cq, nselp, mwords, Pmaxi);
  k_attn<<<dim3(NB*NSTEP), dim3(128), 0, stream>>>(
      question, qs_table, emb_q, emb_s, CPAD, Hfull, Cq,
      nselp, mwords, Pmaxi, out);
}

// Round 5
// 385.520 us; speedup vs baseline: 1.0858x; 1.0185x over previous
//
#include <hip/hip_runtime.h>
#include <stdint.h>

#define NB 32
#define SEQ 128
#define EMB 128
#define NSTEP 127
#define NS 512

__device__ __forceinline__ float ftanh(float x){ float e=__expf(2.f*x); return 1.f-2.f/(e+1.f); }
__device__ __forceinline__ float fsig(float x){ return 1.f/(1.f+__expf(-x)); }
__device__ __forceinline__ float4 ld4(const float* p){ return *(const float4*)p; }

// ---------------------------------------------------------------------------
// Streamed-WT GEMM: out[r,e] = bias[e] + sum_k X[r,k] * WT[k,e]
// X in LDS [R][XS]; WT global row-major [K][NEtot] (pre-transposed).
// NAMED register double groups only — any VGPR array with non-constant index
// is demoted to scratch (prior session: 256 VGPR + 554 MB scratch traffic).
// ---------------------------------------------------------------------------
#define FMA4(acc, xv, a0, a1, a2, a3) \
  acc.x = fmaf(xv.x, a0.x, fmaf(xv.y, a1.x, fmaf(xv.z, a2.x, fmaf(xv.w, a3.x, acc.x)))); \
  acc.y = fmaf(xv.x, a0.y, fmaf(xv.y, a1.y, fmaf(xv.z, a2.y, fmaf(xv.w, a3.y, acc.y)))); \
  acc.z = fmaf(xv.x, a0.z, fmaf(xv.y, a1.z, fmaf(xv.z, a2.z, fmaf(xv.w, a3.z, acc.z)))); \
  acc.w = fmaf(xv.x, a0.w, fmaf(xv.y, a1.w, fmaf(xv.z, a2.w, fmaf(xv.w, a3.w, acc.w))));

// gemm8: 128-thr blocks, 1 row per thread (32 et x 4 rt). Used by k_pre/k_pre2.
template<int K, int XS>
__device__ __forceinline__ void gemm8(const float* __restrict__ WT, int NEtot,
                                      const float* Xl, const float* __restrict__ bias,
                                      float* outb)
{
  const int tid = threadIdx.x;
  const int et = tid & 31;
  const int rt = tid >> 5;
  const float* wp = WT + et*4;
  const float* xr = Xl + rt*XS;
  constexpr int G = K/4;
  float4 acc = {0.f,0.f,0.f,0.f};
  float4 w0 = ld4(wp);
  float4 w1 = ld4(wp + NEtot);
  float4 w2 = ld4(wp + 2*NEtot);
  float4 w3 = ld4(wp + 3*NEtot);
  const float* wq = wp + (size_t)4*NEtot;
  float4 m0 = ld4(wq);
  float4 m1 = ld4(wq + NEtot);
  float4 m2 = ld4(wq + 2*NEtot);
  float4 m3 = ld4(wq + 3*NEtot);
  #pragma unroll 2
  for (int g = 0; g + 2 < G; g += 2) {
    const float* wa = wp + (size_t)(4*(g+2))*NEtot;
    float4 n0 = ld4(wa);
    float4 n1 = ld4(wa + NEtot);
    float4 n2 = ld4(wa + 2*NEtot);
    float4 n3 = ld4(wa + 3*NEtot);
    float4 xa = ld4(xr + 4*g);
    FMA4(acc, xa, w0, w1, w2, w3);
    w0=n0; w1=n1; w2=n2; w3=n3;
    const float* wb = wp + (size_t)(4*(g+3))*NEtot;
    float4 o0 = ld4(wb);
    float4 o1 = ld4(wb + NEtot);
    float4 o2 = ld4(wb + 2*NEtot);
    float4 o3 = ld4(wb + 3*NEtot);
    float4 xb = ld4(xr + 4*(g+1));
    FMA4(acc, xb, m0, m1, m2, m3);
    m0=o0; m1=o1; m2=o2; m3=o3;
  }
  {
    float4 xa = ld4(xr + 4*(G-2));
    FMA4(acc, xa, w0, w1, w2, w3);
    float4 xb = ld4(xr + 4*(G-1));
    FMA4(acc, xb, m0, m1, m2, m3);
  }
  float4 bb = ld4(bias + et*4);
  acc.x+=bb.x; acc.y+=bb.y; acc.z+=bb.z; acc.w+=bb.w;
  *(float4*)(outb + rt*132 + et*4) = acc;
}

// ---------------------------------------------------------------------------
// gemmKS: 512-thr blocks, K-SPLIT. et=tid&31 (4 cols, float4 loads),
// kt=(tid>>5)&1 (half of K each), rg=tid>>6 (8 groups x NR=2 rows = 16 rows).
// kt=0 adds bias and writes outb; kt=1 writes raw partial to partb.
// Caller must sum outb+partb after the following __syncthreads.
// ---------------------------------------------------------------------------
template<int K, int XS>
__device__ __forceinline__ void gemmKS(const float* __restrict__ WT, int NEtot,
                                       const float* Xl, const float* __restrict__ bias,
                                       float* outb, float* partb)
{
  const int tid = threadIdx.x;
  const int et = tid & 31;
  const int kt = (tid >> 5) & 1;
  const int rg = tid >> 6;                 // 0..7
  constexpr int KH = K/2;
  constexpr int G  = KH/4;
  const float* wp = WT + (size_t)kt*KH*NEtot + et*4;
  const float* xr = Xl + (size_t)(rg*2)*XS + kt*KH;
  float4 a0 = {0.f,0.f,0.f,0.f};
  float4 a1 = {0.f,0.f,0.f,0.f};
  float4 w0 = ld4(wp);
  float4 w1 = ld4(wp + NEtot);
  float4 w2 = ld4(wp + 2*NEtot);
  float4 w3 = ld4(wp + 3*NEtot);
  const float* wq = wp + (size_t)4*NEtot;
  float4 m0 = ld4(wq);
  float4 m1 = ld4(wq + NEtot);
  float4 m2 = ld4(wq + 2*NEtot);
  float4 m3 = ld4(wq + 3*NEtot);
  #pragma unroll 2
  for (int g = 0; g + 2 < G; g += 2) {
    const float* wa = wp + (size_t)(4*(g+2))*NEtot;
    float4 n0 = ld4(wa);
    float4 n1 = ld4(wa + NEtot);
    float4 n2 = ld4(wa + 2*NEtot);
    float4 n3 = ld4(wa + 3*NEtot);
    float4 xa0 = ld4(xr + 4*g);
    float4 xa1 = ld4(xr + XS + 4*g);
    FMA4(a0, xa0, w0, w1, w2, w3);
    FMA4(a1, xa1, w0, w1, w2, w3);
    w0=n0; w1=n1; w2=n2; w3=n3;
    const float* wb = wp + (size_t)(4*(g+3))*NEtot;
    float4 o0 = ld4(wb);
    float4 o1 = ld4(wb + NEtot);
    float4 o2 = ld4(wb + 2*NEtot);
    float4 o3 = ld4(wb + 3*NEtot);
    float4 xb0 = ld4(xr + 4*(g+1));
    float4 xb1 = ld4(xr + XS + 4*(g+1));
    FMA4(a0, xb0, m0, m1, m2, m3);
    FMA4(a1, xb1, m0, m1, m2, m3);
    m0=o0; m1=o1; m2=o2; m3=o3;
  }
  {
    float4 xa0 = ld4(xr + 4*(G-2));
    float4 xa1 = ld4(xr + XS + 4*(G-2));
    FMA4(a0, xa0, w0, w1, w2, w3);
    FMA4(a1, xa1, w0, w1, w2, w3);
    float4 xb0 = ld4(xr + 4*(G-1));
    float4 xb1 = ld4(xr + XS + 4*(G-1));
    FMA4(a0, xb0, m0, m1, m2, m3);
    FMA4(a1, xb1, m0, m1, m2, m3);
  }
  float* dst;
  if (kt == 0) {
    float4 bb = ld4(bias + et*4);
    a0.x+=bb.x; a0.y+=bb.y; a0.z+=bb.z; a0.w+=bb.w;
    a1.x+=bb.x; a1.y+=bb.y; a1.z+=bb.z; a1.w+=bb.w;
    dst = outb;
  } else {
    dst = partb;
  }
  float* ob = dst + (size_t)(rg*2)*132 + et*4;
  *(float4*)(ob)       = a0;
  *(float4*)(ob + 132) = a1;
}

// ---------------------------------------------------------------------------
// k_T: transpose weights into ws, BIH = b_ih+b_hh, c_pad, zero G1/Pmaxi.
// NEW: WIHT keeps only the h-half of W_ih (K=128), and ER2[2][512] holds the
// precomputed emb_r-half contribution emb_r[r] @ W_ih[:,128:256]^T (r_t is
// binary -> the K=256 LSTM contraction collapses to K=128 + table add).
// ---------------------------------------------------------------------------
__global__ __launch_bounds__(256) void k_T(
    const float* __restrict__ W_agg, const float* __restrict__ W_last,
    const float* __restrict__ W_query, const float* __restrict__ W_ih,
    const float* __restrict__ b_ih, const float* __restrict__ b_hh,
    const float* __restrict__ b_query, const float* __restrict__ w_W,
    const float* __restrict__ emb_r,
    float* __restrict__ WT012, float* __restrict__ WLT, float* __restrict__ WQT,
    float* __restrict__ WIHT, float* __restrict__ ER2,
    float* __restrict__ BIH, float* __restrict__ CPAD,
    float* __restrict__ G1, int* __restrict__ Pmaxi)
{
  const int gid = blockIdx.x*256 + threadIdx.x;
  const int gsz = gridDim.x*256;
  for (int i = gid; i < 49152; i += gsz) {
    int j = i >> 14, rem = i & 16383, k = rem >> 7, e = rem & 127;
    WT012[i] = W_agg[j*16384 + e*128 + k];
  }
  for (int i = gid; i < 16384; i += gsz) {
    int k = i >> 7, e = i & 127;
    WLT[i] = W_last[e*128 + k];
    WQT[i] = W_query[e*128 + k];
  }
  for (int i = gid; i < 65536; i += gsz) {
    int k = i >> 9, e = i & 511;
    WIHT[i] = W_ih[e*256 + k];
  }
  for (int i = gid; i < 1024; i += gsz) {
    int r = i >> 9, c = i & 511;
    const float* wcol = W_ih + (size_t)c*256 + 128;
    const float* er = emb_r + r*128;
    float acc = 0.f;
    #pragma unroll 4
    for (int k = 0; k < 128; k += 4) {
      acc = fmaf(er[k], wcol[k],
            fmaf(er[k+1], wcol[k+1],
            fmaf(er[k+2], wcol[k+2],
            fmaf(er[k+3], wcol[k+3], acc))));
    }
    ER2[i] = acc;
  }
  for (int i = gid; i < 65536; i += gsz) G1[i] = 0.f;
  if (gid < 512) BIH[gid] = b_ih[gid] + b_hh[gid];
  if (gid < 128) Pmaxi[gid] = 0;
  if (blockIdx.x == 0) {
    __shared__ float red[256];
    float v = (threadIdx.x < 128) ? ftanh(b_query[threadIdx.x]) * w_W[128 + threadIdx.x] : 0.f;
    red[threadIdx.x] = v; __syncthreads();
    #pragma unroll
    for (int s = 128; s > 0; s >>= 1) {
      if (threadIdx.x < s) red[threadIdx.x] += red[threadIdx.x + s];
      __syncthreads();
    }
    if (threadIdx.x == 0) CPAD[0] = red[0];
  }
}

// ---------------------------------------------------------------------------
// k_pre: 128-thr blocks, 4 rows each. Blocks 0..127: E1 (4 s-rows).
// Blocks 128..1407: 4 of 5120 (s,j) level-2 pairs, atomicAdd into G1.
// ---------------------------------------------------------------------------
__global__ __launch_bounds__(128) void k_pre(
    const int* __restrict__ s_neighbors, const int* __restrict__ q_neighbors,
    const float* __restrict__ emb_q, const float* __restrict__ emb_s,
    const float* __restrict__ WT012, const float* __restrict__ b_agg,
    float* __restrict__ E1, float* __restrict__ G1)
{
  __shared__ float XA[4*132];
  __shared__ float XB[4*132];
  __shared__ int idx[40];
  __shared__ int n3[16];
  const int tid = threadIdx.x;
  const int blk = blockIdx.x;
  if (blk < 128) {
    const int s0 = blk*4;
    if (tid < 40) idx[tid] = s_neighbors[s0*10 + tid];
    __syncthreads();
    {
      int r = tid >> 5, e4 = (tid & 31) << 2;
      float4 a = ld4(emb_s + (size_t)(s0+r)*128 + e4);
      float sx=0,sy=0,sz=0,sw=0;
      #pragma unroll
      for (int jj = 0; jj < 10; ++jj) {
        float4 q = ld4(emb_q + (size_t)idx[r*10+jj]*128 + e4);
        sx+=q.x; sy+=q.y; sz+=q.z; sw+=q.w;
      }
      float4 o; o.x=a.x+0.1f*sx; o.y=a.y+0.1f*sy; o.z=a.z+0.1f*sz; o.w=a.w+0.1f*sw;
      *(float4*)(XA + r*132 + e4) = o;
    }
    __syncthreads();
    gemm8<128,132>(WT012 + 16384, 128, XA, b_agg + 128, XB);
    __syncthreads();
    for (int f = tid; f < 512; f += 128) {
      int r = f >> 7, e = f & 127;
      E1[(size_t)(s0+r)*128 + e] = ftanh(XB[r*132 + e]);
    }
  } else {
    const int p0 = (blk-128)*4;
    if (tid < 4) idx[tid] = s_neighbors[p0 + tid];
    __syncthreads();
    if (tid < 16) n3[tid] = q_neighbors[(size_t)idx[tid>>2]*4 + (tid&3)];
    __syncthreads();
    {
      int r = tid >> 5, e4 = (tid & 31) << 2;
      float4 a = ld4(emb_q + (size_t)idx[r]*128 + e4);
      float sx=0,sy=0,sz=0,sw=0;
      #pragma unroll
      for (int k = 0; k < 4; ++k) {
        float4 q = ld4(emb_s + (size_t)n3[r*4+k]*128 + e4);
        sx+=q.x; sy+=q.y; sz+=q.z; sw+=q.w;
      }
      float4 o; o.x=a.x+0.25f*sx; o.y=a.y+0.25f*sy; o.z=a.z+0.25f*sz; o.w=a.w+0.25f*sw;
      *(float4*)(XA + r*132 + e4) = o;
    }
    __syncthreads();
    gemm8<128,132>(WT012 + 32768, 128, XA, b_agg + 256, XB);
    __syncthreads();
    for (int f = tid; f < 512; f += 128) {
      int r = f >> 7, e = f & 127;
      atomicAdd(&G1[(size_t)((p0+r)/10)*128 + e], ftanh(XB[r*132 + e]));
    }
  }
}

// k_pre2: E2[s] = tanh((0.1*G1[s] + E1[s]) @ W1.T + b1)  (128 blocks x 4 rows)
__global__ __launch_bounds__(128) void k_pre2(
    const float* __restrict__ E1, const float* __restrict__ G1,
    const float* __restrict__ WT012, const float* __restrict__ b_agg,
    float* __restrict__ E2)
{
  __shared__ float XA[4*132];
  __shared__ float XB[4*132];
  const int tid = threadIdx.x;
  const int s0 = blockIdx.x*4;
  for (int f = tid; f < 512; f += 128) {
    int r = f >> 7, e = f & 127;
    XA[r*132 + e] = 0.1f*G1[(size_t)(s0+r)*128 + e] + E1[(size_t)(s0+r)*128 + e];
  }
  __syncthreads();
  gemm8<128,132>(WT012 + 16384, 128, XA, b_agg + 128, XB);
  __syncthreads();
  for (int f = tid; f < 512; f += 128) {
    int r = f >> 7, e = f & 127;
    E2[(size_t)(s0+r)*128 + e] = ftanh(XB[r*132 + e]);
  }
}

// ---------------------------------------------------------------------------
// k_chain: 254 blocks x 512 thr x 16 (b,t)-rows, K-split gemms.
// LSTM gates now K=128 (h-half only); the emb_r-half comes from the ER2 table
// added in the merge loops. Per-block weight stream 704KB -> 512KB; FMA -27%.
// LDS 50.9KB. Fused k_match at the tail (8 waves x 2 rows).
// ---------------------------------------------------------------------------
__global__ __launch_bounds__(512) void k_chain(
    const int* __restrict__ question, const int* __restrict__ response,
    const int* __restrict__ maskp, const int* __restrict__ q_neighbors,
    const int* __restrict__ s_neighbors,
    const float* __restrict__ emb_q, const float* __restrict__ emb_s,
    const float* __restrict__ WT012, const float* __restrict__ WLT,
    const float* __restrict__ WQT, const float* __restrict__ WIHT,
    const float* __restrict__ ER2, const float* __restrict__ BIH,
    const float* __restrict__ b_agg, const float* __restrict__ b_last,
    const float* __restrict__ b_query, const float* __restrict__ w_W,
    const float* __restrict__ E1, const float* __restrict__ E2,
    float* __restrict__ Hfull, float* __restrict__ Cq,
    int* __restrict__ nsel, unsigned long long* __restrict__ mwords,
    int* __restrict__ Pmaxi)
{
  __shared__ float XA[16*132];
  __shared__ float XB[16*132];
  __shared__ float M1[16*132];
  __shared__ float M2[16*132];
  __shared__ float PB[16*132];   // K-split partial
  __shared__ float XC[16*132];   // h only (emb_r half replaced by ER2 table)
  __shared__ int qts[16], rts[16], mts[16], n1s[64];

  const int tid = threadIdx.x;
  const int blk = blockIdx.x;

  if (tid < 16) {
    int rid = blk*16 + tid;
    int b = rid / 127, t = rid - b*127;
    qts[tid] = question[b*SEQ + t];
    rts[tid] = response[b*SEQ + t];
    mts[tid] = maskp[b*SEQ + t];
  }
  __syncthreads();
  if (tid < 64) n1s[tid] = q_neighbors[(size_t)qts[tid>>2]*4 + (tid&3)];
  __syncthreads();
  // XA = emb_q[qt] + 0.25*sum emb_s[n1]; M1 = 0.25*sum E1[n1]; M2 = 0.25*sum E2[n1]
  {
    const int e4 = (tid & 31) << 2;
    const int rr = tid >> 5;   // 0..15
    const int* nn = n1s + rr*4;
    float4 a = ld4(emb_q + (size_t)qts[rr]*128 + e4);
    float s1x=0,s1y=0,s1z=0,s1w=0, s2x=0,s2y=0,s2z=0,s2w=0, s3x=0,s3y=0,s3z=0,s3w=0;
    #pragma unroll
    for (int i = 0; i < 4; ++i) {
      float4 q1 = ld4(emb_s + (size_t)nn[i]*128 + e4);
      float4 q2 = ld4(E1 + (size_t)nn[i]*128 + e4);
      float4 q3 = ld4(E2 + (size_t)nn[i]*128 + e4);
      s1x+=q1.x; s1y+=q1.y; s1z+=q1.z; s1w+=q1.w;
      s2x+=q2.x; s2y+=q2.y; s2z+=q2.z; s2w+=q2.w;
      s3x+=q3.x; s3y+=q3.y; s3z+=q3.z; s3w+=q3.w;
    }
    float4 o; o.x=a.x+0.25f*s1x; o.y=a.y+0.25f*s1y; o.z=a.z+0.25f*s1z; o.w=a.w+0.25f*s1w;
    *(float4*)(XA + rr*132 + e4) = o;
    float4 p; p.x=0.25f*s2x; p.y=0.25f*s2y; p.z=0.25f*s2z; p.w=0.25f*s2w;
    *(float4*)(M1 + rr*132 + e4) = p;
    float4 u; u.x=0.25f*s3x; u.y=0.25f*s3y; u.z=0.25f*s3z; u.w=0.25f*s3w;
    *(float4*)(M2 + rr*132 + e4) = u;
  }
  // 3-stage aggregation chain (each act-loop also merges the K-split partial)
  __syncthreads();
  gemmKS<128,132>(WT012, 128, XA, b_agg, XB, PB);     // e0_1 pre-act
  __syncthreads();
  for (int f = tid; f < 2048; f += 512) {
    int i = (f >> 7)*132 + (f & 127);
    XB[i] = M1[i] + ftanh(XB[i] + PB[i]);
  }
  __syncthreads();
  gemmKS<128,132>(WT012, 128, XB, b_agg, XA, PB);     // e0_2 pre-act
  __syncthreads();
  for (int f = tid; f < 2048; f += 512) {
    int i = (f >> 7)*132 + (f & 127);
    XA[i] = M2[i] + ftanh(XA[i] + PB[i]);
  }
  __syncthreads();
  gemmKS<128,132>(WT012, 128, XA, b_agg, XB, PB);     // e0_3 pre-act
  __syncthreads();
  for (int f = tid; f < 2048; f += 512) {
    int i = (f >> 7)*132 + (f & 127);
    XB[i] = ftanh(XB[i] + PB[i]);
  }
  __syncthreads();
  gemmKS<128,132>(WLT, 128, XB, b_last, XA, PB);      // agg pre-act
  __syncthreads();
  for (int f = tid; f < 2048; f += 512) {
    int r = f >> 7, e = f & 127, i = r*132 + e;
    float agg = ftanh(XA[i] + PB[i]);
    XC[i] = (mts[r] == 1) ? agg : emb_q[(size_t)qts[r]*128 + e];
  }
  __syncthreads();
  // LSTM gates gi/gg/go, K=128 (h part); emb_r part from ER2 table.
  gemmKS<128,132>(WIHT,       512, XC, BIH,       XA, PB);
  __syncthreads();
  for (int f = tid; f < 2048; f += 512) {
    int r = f >> 7, e = f & 127, i = r*132 + e;
    XA[i] += PB[i] + ER2[rts[r]*512 + e];
  }
  __syncthreads();
  gemmKS<128,132>(WIHT + 256, 512, XC, BIH + 256, XB, PB);
  __syncthreads();
  for (int f = tid; f < 2048; f += 512) {
    int r = f >> 7, e = f & 127, i = r*132 + e;
    XB[i] += PB[i] + ER2[rts[r]*512 + 256 + e];
  }
  __syncthreads();
  gemmKS<128,132>(WIHT + 384, 512, XC, BIH + 384, M1, PB);
  __syncthreads();
  for (int f = tid; f < 2048; f += 512) {
    int r = f >> 7, e = f & 127, i = r*132 + e;
    float gi = XA[i], gg = XB[i];
    float go = M1[i] + PB[i] + ER2[rts[r]*512 + 384 + e];
    float h = fsig(go) * ftanh(fsig(gi) * ftanh(gg));
    XC[i] = h;
    Hfull[(size_t)(blk*16 + r)*128 + e] = h;
  }
  __syncthreads();
  gemmKS<128,132>(WQT, 128, XC, b_query, XA, PB);     // c pre-act
  __syncthreads();
  {
    const int et = tid & 31, rr = tid >> 5;   // 16 rows exactly
    float4 wv = ld4(w_W + 128 + et*4);
    float4 o = ld4(XA + rr*132 + et*4);
    float4 p = ld4(PB + rr*132 + et*4);
    float s = ftanh(o.x+p.x)*wv.x + ftanh(o.y+p.y)*wv.y
            + ftanh(o.z+p.z)*wv.z + ftanh(o.w+p.w)*wv.w;
    #pragma unroll
    for (int off = 16; off > 0; off >>= 1) s += __shfl_down(s, off);
    if (et == 0) Cq[blk*16 + rr] = s;
  }
  // ---- fused k_match: wave w handles rows w and w+8 ----
  {
    const int wv = tid >> 6;      // wave 0..7
    const int ln = tid & 63;      // lane 0..63
    for (int rr = wv; rr < 16; rr += 8) {
      int rid = blk*16 + rr;
      int b = rid / 127, t = rid - b*127;
      int q_next = question[b*SEQ + t + 1];
      int qrv = 0;
      if (ln < 40)
        qrv = s_neighbors[(size_t)q_neighbors[(size_t)q_next*4 + ln/10]*10 + ln%10];
      int q0 = question[b*SEQ + ln];
      int q1 = question[b*SEQ + 64 + ln];
      bool p0 = false, p1 = false;
      #pragma unroll 8
      for (int i = 0; i < 40; ++i) {
        int qv = __shfl(qrv, i);
        p0 |= (q0 == qv); p1 |= (q1 == qv);
      }
      p0 &= (ln < t);
      p1 &= (64 + ln < t);
      unsigned long long w0 = __ballot(p0);
      unsigned long long w1 = __ballot(p1);
      if (ln == 0) {
        size_t bt = (size_t)b*NSTEP + t;
        mwords[bt*2 + 0] = w0;
        mwords[bt*2 + 1] = w1;
        int ns = __popcll(w0) + __popcll(w1);
        nsel[bt] = ns;
        atomicMax(&Pmaxi[t], ns);
      }
    }
  }
}

__device__ __forceinline__ float wredsum(float v) {
  #pragma unroll
  for (int o = 32; o > 0; o >>= 1) v += __shfl_down(v, o);
  return v;
}
__device__ __forceinline__ float wredmax(float v) {
  #pragma unroll
  for (int o = 32; o > 0; o >>= 1) v = fmaxf(v, __shfl_down(v, o));
  return v;
}

// ---------------------------------------------------------------------------
// k_attn: collapsed attention (a[q] cancels across the softmax), y -> out
// ---------------------------------------------------------------------------
__global__ __launch_bounds__(128) void k_attn(
    const int* __restrict__ question, const float* __restrict__ qs_table,
    const float* __restrict__ emb_q, const float* __restrict__ emb_s,
    const float* __restrict__ CPAD,
    const float* __restrict__ Hfull, const float* __restrict__ Cq,
    const int* __restrict__ nsel, const unsigned long long* __restrict__ mwords,
    const int* __restrict__ Pmaxi, float* __restrict__ out)
{
  __shared__ float us[128];
  __shared__ int cols[8];
  __shared__ int cnt;
  __shared__ float smx[2];
  __shared__ float s3[2][3];
  const int tid = threadIdx.x;
  const int wid = tid >> 6;
  const int bid = blockIdx.x;
  const int b = bid / NSTEP, t = bid % NSTEP;
  const size_t bt = (size_t)b*NSTEP + t;
  const int q_next = question[b*SEQ + t + 1];

  if (tid == 0) cnt = 0;
  __syncthreads();
  {
    float4 v = ld4(qs_table + (size_t)q_next*NS + tid*4);
    if (v.x > 0.f) { int p = atomicAdd(&cnt, 1); if (p < 8) cols[p] = tid*4; }
    if (v.y > 0.f) { int p = atomicAdd(&cnt, 1); if (p < 8) cols[p] = tid*4+1; }
    if (v.z > 0.f) { int p = atomicAdd(&cnt, 1); if (p < 8) cols[p] = tid*4+2; }
    if (v.w > 0.f) { int p = atomicAdd(&cnt, 1); if (p < 8) cols[p] = tid*4+3; }
  }
  __syncthreads();
  const int nc = min(cnt, 4);
  {
    float ue = emb_q[(size_t)q_next*EMB + tid];
    for (int i = 0; i < nc; ++i) ue += emb_s[(size_t)cols[i]*EMB + tid];
    us[tid] = ue;
  }
  const float c_pad = CPAD[0];
  const float P = (float)(Pmaxi[t] - nsel[bt]);

  const unsigned long long w0 = mwords[bt*2 + 0];
  const unsigned long long w1 = mwords[bt*2 + 1];
  const bool matched = (tid < 64) ? ((w0 >> tid) & 1ull)
                                  : ((w1 >> (tid - 64)) & 1ull);
  const float c_cur = Cq[bt];
  float Cp = matched ? ((tid == 0) ? c_pad : Cq[(size_t)b*NSTEP + tid]) : -3.0e38f;
  float mh = wredmax(Cp);
  if ((tid & 63) == 0) smx[wid] = mh;
  __syncthreads();   // also publishes us[]
  float M = fmaxf(fmaxf(smx[0], smx[1]), fmaxf(c_cur, c_pad));
  float wgt = matched ? __expf(Cp - M) : 0.f;
  float dotp = 0.f;
  if (matched && tid >= 1) {  // p=0 history row is zeros
    const float* hp = Hfull + ((size_t)b*NSTEP + tid)*EMB;
    float s = 0.f;
    #pragma unroll 8
    for (int e = 0; e < 128; e += 4) {
      float4 h4 = ld4(hp + e);
      s = fmaf(us[e],h4.x, fmaf(us[e+1],h4.y, fmaf(us[e+2],h4.z, fmaf(us[e+3],h4.w, s))));
    }
    dotp = s;
  }
  float gcp = us[tid] * Hfull[bt*EMB + tid];
  float a0 = wredsum(wgt);
  float a1 = wredsum(wgt * dotp);
  float a2 = wredsum(gcp);
  if ((tid & 63) == 0) { s3[wid][0] = a0; s3[wid][1] = a1; s3[wid][2] = a2; }
  __syncthreads();
  if (tid == 0) {
    float Sexp = s3[0][0] + s3[1][0];
    float Snum = s3[0][1] + s3[1][1];
    float gc   = s3[0][2] + s3[1][2];
    float Ec = __expf(c_cur - M), Ep = __expf(c_pad - M);
    float D = Sexp + Ec + P * Ep;
    float numt = Snum + Ec * gc;
    out[b*SEQ + t + 1] = fsig(numt / D);
    if (t == 0) out[b*SEQ] = 0.5f;
  }
}

extern "C" void kernel_launch(void* const* d_in, const int* in_sizes, int n_in,
                              void* d_out, int out_size, void* d_ws, size_t ws_size,
                              hipStream_t stream) {
  const int* question    = (const int*)d_in[0];
  const int* response    = (const int*)d_in[1];
  const int* maskp       = (const int*)d_in[2];
  const int* q_neighbors = (const int*)d_in[3];
  const int* s_neighbors = (const int*)d_in[4];
  const float* qs_table  = (const float*)d_in[5];
  const float* emb_q     = (const float*)d_in[6];
  const float* emb_s     = (const float*)d_in[7];
  const float* emb_r     = (const float*)d_in[8];
  const float* W_ih      = (const float*)d_in[9];
  const float* b_ih      = (const float*)d_in[10];
  const float* b_hh      = (const float*)d_in[11];
  const float* W_agg     = (const float*)d_in[12];
  const float* b_agg     = (const float*)d_in[13];
  const float* W_last    = (const float*)d_in[14];
  const float* b_last    = (const float*)d_in[15];
  const float* W_query   = (const float*)d_in[16];
  const float* b_query   = (const float*)d_in[17];
  // d_in[18] W_key, d_in[19] b_key, d_in[21] b_W: no effect (a[q] cancels)
  const float* w_W       = (const float*)d_in[20];
  float* out = (float*)d_out;

  float* ws = (float*)d_ws;
  float* WT012 = ws;                    // 49152
  float* WLT   = ws + 49152;            // 16384
  float* WQT   = ws + 65536;            // 16384
  float* WIHT  = ws + 81920;            // 65536  [128][512] (h-half only)
  float* ER2   = ws + 147456;           // 1024   [2][512]
  float* BIH   = ws + 212992;           // 512
  float* CPAD  = ws + 213504;           // 16
  float* E1    = ws + 213520;           // 65536
  float* G1    = ws + 279056;           // 65536
  float* E2    = ws + 344592;           // 65536
  float* Hfull = ws + 410128;           // 520192
  float* Cq    = ws + 930320;           // 4064
  int*   Pmaxi = (int*)(ws + 934384);   // 128
  int*   nselp = (int*)(ws + 934512);   // 4064
  unsigned long long* mwords =
      (unsigned long long*)(((uintptr_t)(ws + 938576) + 15) & ~(uintptr_t)15);

  k_T<<<dim3(512), dim3(256), 0, stream>>>(
      W_agg, W_last, W_query, W_ih, b_ih, b_hh, b_query, w_W, emb_r,
      WT012, WLT, WQT, WIHT, ER2, BIH, CPAD, G1, Pmaxi);
  k_pre<<<dim3(1408), dim3(128), 0, stream>>>(
      s_neighbors, q_neighbors, emb_q, emb_s, WT012, b_agg, E1, G1);
  k_pre2<<<dim3(128), dim3(128), 0, stream>>>(E1, G1, WT012, b_agg, E2);
  k_chain<<<dim3(254), dim3(512), 0, stream>>>(
      question, response, maskp, q_neighbors, s_neighbors, emb_q, emb_s,
      WT012, WLT, WQT, WIHT, ER2, BIH, b_agg, b_last, b_query, w_W,
      E1, E2, Hfull, Cq, nselp, mwords, Pmaxi);
  k_attn<<<dim3(NB*NSTEP), dim3(128), 0, stream>>>(
      question, qs_table, emb_q, emb_s, CPAD, Hfull, Cq,
      nselp, mwords, Pmaxi, out);
}

// Round 6
// 382.314 us; speedup vs baseline: 1.0949x; 1.0084x over previous
//
#include <hip/hip_runtime.h>
#include <stdint.h>

#define NB 32
#define SEQ 128
#define EMB 128
#define NSTEP 127
#define NS 512

__device__ __forceinline__ float ftanh(float x){ float e=__expf(2.f*x); return 1.f-2.f/(e+1.f); }
__device__ __forceinline__ float fsig(float x){ return 1.f/(1.f+__expf(-x)); }
__device__ __forceinline__ float4 ld4(const float* p){ return *(const float4*)p; }

// ---------------------------------------------------------------------------
// Streamed-WT GEMM: out[r,e] = bias[e] + sum_k X[r,k] * WT[k,e]
// X in LDS [R][XS]; WT global row-major [K][NEtot] (pre-transposed).
// NAMED register double groups only — any VGPR array with non-constant index
// is demoted to scratch (prior session: 256 VGPR + 554 MB scratch traffic).
// ---------------------------------------------------------------------------
#define FMA4(acc, xv, a0, a1, a2, a3) \
  acc.x = fmaf(xv.x, a0.x, fmaf(xv.y, a1.x, fmaf(xv.z, a2.x, fmaf(xv.w, a3.x, acc.x)))); \
  acc.y = fmaf(xv.x, a0.y, fmaf(xv.y, a1.y, fmaf(xv.z, a2.y, fmaf(xv.w, a3.y, acc.y)))); \
  acc.z = fmaf(xv.x, a0.z, fmaf(xv.y, a1.z, fmaf(xv.z, a2.z, fmaf(xv.w, a3.z, acc.z)))); \
  acc.w = fmaf(xv.x, a0.w, fmaf(xv.y, a1.w, fmaf(xv.z, a2.w, fmaf(xv.w, a3.w, acc.w))));

// ---------------------------------------------------------------------------
// gemmKS: 512-thr blocks, K-SPLIT. et=tid&31 (4 cols, float4 loads),
// kt=(tid>>5)&1 (half of K each), rg=tid>>6 (8 groups x NR=2 rows = 16 rows).
// kt=0 adds bias and writes outb; kt=1 writes raw partial to partb.
// Caller must sum outb+partb after the following __syncthreads.
// ---------------------------------------------------------------------------
template<int K, int XS>
__device__ __forceinline__ void gemmKS(const float* __restrict__ WT, int NEtot,
                                       const float* Xl, const float* __restrict__ bias,
                                       float* outb, float* partb)
{
  const int tid = threadIdx.x;
  const int et = tid & 31;
  const int kt = (tid >> 5) & 1;
  const int rg = tid >> 6;                 // 0..7
  constexpr int KH = K/2;
  constexpr int G  = KH/4;
  const float* wp = WT + (size_t)kt*KH*NEtot + et*4;
  const float* xr = Xl + (size_t)(rg*2)*XS + kt*KH;
  float4 a0 = {0.f,0.f,0.f,0.f};
  float4 a1 = {0.f,0.f,0.f,0.f};
  float4 w0 = ld4(wp);
  float4 w1 = ld4(wp + NEtot);
  float4 w2 = ld4(wp + 2*NEtot);
  float4 w3 = ld4(wp + 3*NEtot);
  const float* wq = wp + (size_t)4*NEtot;
  float4 m0 = ld4(wq);
  float4 m1 = ld4(wq + NEtot);
  float4 m2 = ld4(wq + 2*NEtot);
  float4 m3 = ld4(wq + 3*NEtot);
  #pragma unroll 2
  for (int g = 0; g + 2 < G; g += 2) {
    const float* wa = wp + (size_t)(4*(g+2))*NEtot;
    float4 n0 = ld4(wa);
    float4 n1 = ld4(wa + NEtot);
    float4 n2 = ld4(wa + 2*NEtot);
    float4 n3 = ld4(wa + 3*NEtot);
    float4 xa0 = ld4(xr + 4*g);
    float4 xa1 = ld4(xr + XS + 4*g);
    FMA4(a0, xa0, w0, w1, w2, w3);
    FMA4(a1, xa1, w0, w1, w2, w3);
    w0=n0; w1=n1; w2=n2; w3=n3;
    const float* wb = wp + (size_t)(4*(g+3))*NEtot;
    float4 o0 = ld4(wb);
    float4 o1 = ld4(wb + NEtot);
    float4 o2 = ld4(wb + 2*NEtot);
    float4 o3 = ld4(wb + 3*NEtot);
    float4 xb0 = ld4(xr + 4*(g+1));
    float4 xb1 = ld4(xr + XS + 4*(g+1));
    FMA4(a0, xb0, m0, m1, m2, m3);
    FMA4(a1, xb1, m0, m1, m2, m3);
    m0=o0; m1=o1; m2=o2; m3=o3;
  }
  {
    float4 xa0 = ld4(xr + 4*(G-2));
    float4 xa1 = ld4(xr + XS + 4*(G-2));
    FMA4(a0, xa0, w0, w1, w2, w3);
    FMA4(a1, xa1, w0, w1, w2, w3);
    float4 xb0 = ld4(xr + 4*(G-1));
    float4 xb1 = ld4(xr + XS + 4*(G-1));
    FMA4(a0, xb0, m0, m1, m2, m3);
    FMA4(a1, xb1, m0, m1, m2, m3);
  }
  float* dst;
  if (kt == 0) {
    float4 bb = ld4(bias + et*4);
    a0.x+=bb.x; a0.y+=bb.y; a0.z+=bb.z; a0.w+=bb.w;
    a1.x+=bb.x; a1.y+=bb.y; a1.z+=bb.z; a1.w+=bb.w;
    dst = outb;
  } else {
    dst = partb;
  }
  float* ob = dst + (size_t)(rg*2)*132 + et*4;
  *(float4*)(ob)       = a0;
  *(float4*)(ob + 132) = a1;
}

// ---------------------------------------------------------------------------
// k_T: transpose weights into ws, BIH = b_ih+b_hh, c_pad, zero G1/Pmaxi.
// WIHT keeps only the h-half of W_ih (K=128); ER2[2][512] holds the
// precomputed emb_r-half contribution (r_t is binary).
// ---------------------------------------------------------------------------
__global__ __launch_bounds__(256) void k_T(
    const float* __restrict__ W_agg, const float* __restrict__ W_last,
    const float* __restrict__ W_query, const float* __restrict__ W_ih,
    const float* __restrict__ b_ih, const float* __restrict__ b_hh,
    const float* __restrict__ b_query, const float* __restrict__ w_W,
    const float* __restrict__ emb_r,
    float* __restrict__ WT012, float* __restrict__ WLT, float* __restrict__ WQT,
    float* __restrict__ WIHT, float* __restrict__ ER2,
    float* __restrict__ BIH, float* __restrict__ CPAD,
    float* __restrict__ G1, int* __restrict__ Pmaxi)
{
  const int gid = blockIdx.x*256 + threadIdx.x;
  const int gsz = gridDim.x*256;
  for (int i = gid; i < 49152; i += gsz) {
    int j = i >> 14, rem = i & 16383, k = rem >> 7, e = rem & 127;
    WT012[i] = W_agg[j*16384 + e*128 + k];
  }
  for (int i = gid; i < 16384; i += gsz) {
    int k = i >> 7, e = i & 127;
    WLT[i] = W_last[e*128 + k];
    WQT[i] = W_query[e*128 + k];
  }
  for (int i = gid; i < 65536; i += gsz) {
    int k = i >> 9, e = i & 511;
    WIHT[i] = W_ih[e*256 + k];
  }
  for (int i = gid; i < 1024; i += gsz) {
    int r = i >> 9, c = i & 511;
    const float* wcol = W_ih + (size_t)c*256 + 128;
    const float* er = emb_r + r*128;
    float acc = 0.f;
    #pragma unroll 4
    for (int k = 0; k < 128; k += 4) {
      acc = fmaf(er[k], wcol[k],
            fmaf(er[k+1], wcol[k+1],
            fmaf(er[k+2], wcol[k+2],
            fmaf(er[k+3], wcol[k+3], acc))));
    }
    ER2[i] = acc;
  }
  for (int i = gid; i < 65536; i += gsz) G1[i] = 0.f;
  if (gid < 512) BIH[gid] = b_ih[gid] + b_hh[gid];
  if (gid < 128) Pmaxi[gid] = 0;
  if (blockIdx.x == 0) {
    __shared__ float red[256];
    float v = (threadIdx.x < 128) ? ftanh(b_query[threadIdx.x]) * w_W[128 + threadIdx.x] : 0.f;
    red[threadIdx.x] = v; __syncthreads();
    #pragma unroll
    for (int s = 128; s > 0; s >>= 1) {
      if (threadIdx.x < s) red[threadIdx.x] += red[threadIdx.x + s];
      __syncthreads();
    }
    if (threadIdx.x == 0) CPAD[0] = red[0];
  }
}

// ---------------------------------------------------------------------------
// k_pre: 512-thr K-split blocks, 16 rows each (k_chain's proven structure).
// Blocks 0..31: E1 (16 s-rows each). Blocks 32..351: 16 of 5120 (s,j)
// level-2 pairs each, atomicAdd into G1. Weight stream 88MB -> 22MB vs the
// old 1408x128thr version; all 4 SIMDs busy; 25.3KB LDS -> 2 blocks/CU.
// ---------------------------------------------------------------------------
__global__ __launch_bounds__(512) void k_pre(
    const int* __restrict__ s_neighbors, const int* __restrict__ q_neighbors,
    const float* __restrict__ emb_q, const float* __restrict__ emb_s,
    const float* __restrict__ WT012, const float* __restrict__ b_agg,
    float* __restrict__ E1, float* __restrict__ G1)
{
  __shared__ float XA[16*132];
  __shared__ float XB[16*132];
  __shared__ float PB[16*132];
  __shared__ int idx[160];
  __shared__ int n3[64];
  const int tid = threadIdx.x;
  const int blk = blockIdx.x;
  if (blk < 32) {
    const int s0 = blk*16;
    if (tid < 160) idx[tid] = s_neighbors[s0*10 + tid];
    __syncthreads();
    {
      const int e4 = (tid & 31) << 2;
      const int rr = tid >> 5;   // 0..15
      float4 a = ld4(emb_s + (size_t)(s0+rr)*128 + e4);
      float sx=0,sy=0,sz=0,sw=0;
      #pragma unroll
      for (int jj = 0; jj < 10; ++jj) {
        float4 q = ld4(emb_q + (size_t)idx[rr*10+jj]*128 + e4);
        sx+=q.x; sy+=q.y; sz+=q.z; sw+=q.w;
      }
      float4 o; o.x=a.x+0.1f*sx; o.y=a.y+0.1f*sy; o.z=a.z+0.1f*sz; o.w=a.w+0.1f*sw;
      *(float4*)(XA + rr*132 + e4) = o;
    }
    __syncthreads();
    gemmKS<128,132>(WT012 + 16384, 128, XA, b_agg + 128, XB, PB);
    __syncthreads();
    for (int f = tid; f < 2048; f += 512) {
      int r = f >> 7, e = f & 127, i = r*132 + e;
      E1[(size_t)(s0+r)*128 + e] = ftanh(XB[i] + PB[i]);
    }
  } else {
    const int p0 = (blk-32)*16;
    if (tid < 16) idx[tid] = s_neighbors[p0 + tid];
    __syncthreads();
    if (tid < 64) n3[tid] = q_neighbors[(size_t)idx[tid>>2]*4 + (tid&3)];
    __syncthreads();
    {
      const int e4 = (tid & 31) << 2;
      const int rr = tid >> 5;   // 0..15
      float4 a = ld4(emb_q + (size_t)idx[rr]*128 + e4);
      float sx=0,sy=0,sz=0,sw=0;
      #pragma unroll
      for (int k = 0; k < 4; ++k) {
        float4 q = ld4(emb_s + (size_t)n3[rr*4+k]*128 + e4);
        sx+=q.x; sy+=q.y; sz+=q.z; sw+=q.w;
      }
      float4 o; o.x=a.x+0.25f*sx; o.y=a.y+0.25f*sy; o.z=a.z+0.25f*sz; o.w=a.w+0.25f*sw;
      *(float4*)(XA + rr*132 + e4) = o;
    }
    __syncthreads();
    gemmKS<128,132>(WT012 + 32768, 128, XA, b_agg + 256, XB, PB);
    __syncthreads();
    for (int f = tid; f < 2048; f += 512) {
      int r = f >> 7, e = f & 127, i = r*132 + e;
      atomicAdd(&G1[(size_t)((p0+r)/10)*128 + e], ftanh(XB[i] + PB[i]));
    }
  }
}

// k_pre2: E2[s] = tanh((0.1*G1[s] + E1[s]) @ W1.T + b1)  (32 blocks x 16 rows)
__global__ __launch_bounds__(512) void k_pre2(
    const float* __restrict__ E1, const float* __restrict__ G1,
    const float* __restrict__ WT012, const float* __restrict__ b_agg,
    float* __restrict__ E2)
{
  __shared__ float XA[16*132];
  __shared__ float XB[16*132];
  __shared__ float PB[16*132];
  const int tid = threadIdx.x;
  const int s0 = blockIdx.x*16;
  for (int f = tid; f < 2048; f += 512) {
    int r = f >> 7, e = f & 127;
    XA[r*132 + e] = 0.1f*G1[(size_t)(s0+r)*128 + e] + E1[(size_t)(s0+r)*128 + e];
  }
  __syncthreads();
  gemmKS<128,132>(WT012 + 16384, 128, XA, b_agg + 128, XB, PB);
  __syncthreads();
  for (int f = tid; f < 2048; f += 512) {
    int r = f >> 7, e = f & 127, i = r*132 + e;
    E2[(size_t)(s0+r)*128 + e] = ftanh(XB[i] + PB[i]);
  }
}

// ---------------------------------------------------------------------------
// k_chain: 254 blocks x 512 thr x 16 (b,t)-rows, K-split gemms.
// LSTM gates K=128 (h-half only); emb_r-half from ER2 table.
// LDS 50.9KB. Fused k_match at the tail (8 waves x 2 rows).
// ---------------------------------------------------------------------------
__global__ __launch_bounds__(512) void k_chain(
    const int* __restrict__ question, const int* __restrict__ response,
    const int* __restrict__ maskp, const int* __restrict__ q_neighbors,
    const int* __restrict__ s_neighbors,
    const float* __restrict__ emb_q, const float* __restrict__ emb_s,
    const float* __restrict__ WT012, const float* __restrict__ WLT,
    const float* __restrict__ WQT, const float* __restrict__ WIHT,
    const float* __restrict__ ER2, const float* __restrict__ BIH,
    const float* __restrict__ b_agg, const float* __restrict__ b_last,
    const float* __restrict__ b_query, const float* __restrict__ w_W,
    const float* __restrict__ E1, const float* __restrict__ E2,
    float* __restrict__ Hfull, float* __restrict__ Cq,
    int* __restrict__ nsel, unsigned long long* __restrict__ mwords,
    int* __restrict__ Pmaxi)
{
  __shared__ float XA[16*132];
  __shared__ float XB[16*132];
  __shared__ float M1[16*132];
  __shared__ float M2[16*132];
  __shared__ float PB[16*132];   // K-split partial
  __shared__ float XC[16*132];   // h only (emb_r half replaced by ER2 table)
  __shared__ int qts[16], rts[16], mts[16], n1s[64];

  const int tid = threadIdx.x;
  const int blk = blockIdx.x;

  if (tid < 16) {
    int rid = blk*16 + tid;
    int b = rid / 127, t = rid - b*127;
    qts[tid] = question[b*SEQ + t];
    rts[tid] = response[b*SEQ + t];
    mts[tid] = maskp[b*SEQ + t];
  }
  __syncthreads();
  if (tid < 64) n1s[tid] = q_neighbors[(size_t)qts[tid>>2]*4 + (tid&3)];
  __syncthreads();
  // XA = emb_q[qt] + 0.25*sum emb_s[n1]; M1 = 0.25*sum E1[n1]; M2 = 0.25*sum E2[n1]
  {
    const int e4 = (tid & 31) << 2;
    const int rr = tid >> 5;   // 0..15
    const int* nn = n1s + rr*4;
    float4 a = ld4(emb_q + (size_t)qts[rr]*128 + e4);
    float s1x=0,s1y=0,s1z=0,s1w=0, s2x=0,s2y=0,s2z=0,s2w=0, s3x=0,s3y=0,s3z=0,s3w=0;
    #pragma unroll
    for (int i = 0; i < 4; ++i) {
      float4 q1 = ld4(emb_s + (size_t)nn[i]*128 + e4);
      float4 q2 = ld4(E1 + (size_t)nn[i]*128 + e4);
      float4 q3 = ld4(E2 + (size_t)nn[i]*128 + e4);
      s1x+=q1.x; s1y+=q1.y; s1z+=q1.z; s1w+=q1.w;
      s2x+=q2.x; s2y+=q2.y; s2z+=q2.z; s2w+=q2.w;
      s3x+=q3.x; s3y+=q3.y; s3z+=q3.z; s3w+=q3.w;
    }
    float4 o; o.x=a.x+0.25f*s1x; o.y=a.y+0.25f*s1y; o.z=a.z+0.25f*s1z; o.w=a.w+0.25f*s1w;
    *(float4*)(XA + rr*132 + e4) = o;
    float4 p; p.x=0.25f*s2x; p.y=0.25f*s2y; p.z=0.25f*s2z; p.w=0.25f*s2w;
    *(float4*)(M1 + rr*132 + e4) = p;
    float4 u; u.x=0.25f*s3x; u.y=0.25f*s3y; u.z=0.25f*s3z; u.w=0.25f*s3w;
    *(float4*)(M2 + rr*132 + e4) = u;
  }
  // 3-stage aggregation chain (each act-loop also merges the K-split partial)
  __syncthreads();
  gemmKS<128,132>(WT012, 128, XA, b_agg, XB, PB);     // e0_1 pre-act
  __syncthreads();
  for (int f = tid; f < 2048; f += 512) {
    int i = (f >> 7)*132 + (f & 127);
    XB[i] = M1[i] + ftanh(XB[i] + PB[i]);
  }
  __syncthreads();
  gemmKS<128,132>(WT012, 128, XB, b_agg, XA, PB);     // e0_2 pre-act
  __syncthreads();
  for (int f = tid; f < 2048; f += 512) {
    int i = (f >> 7)*132 + (f & 127);
    XA[i] = M2[i] + ftanh(XA[i] + PB[i]);
  }
  __syncthreads();
  gemmKS<128,132>(WT012, 128, XA, b_agg, XB, PB);     // e0_3 pre-act
  __syncthreads();
  for (int f = tid; f < 2048; f += 512) {
    int i = (f >> 7)*132 + (f & 127);
    XB[i] = ftanh(XB[i] + PB[i]);
  }
  __syncthreads();
  gemmKS<128,132>(WLT, 128, XB, b_last, XA, PB);      // agg pre-act
  __syncthreads();
  for (int f = tid; f < 2048; f += 512) {
    int r = f >> 7, e = f & 127, i = r*132 + e;
    float agg = ftanh(XA[i] + PB[i]);
    XC[i] = (mts[r] == 1) ? agg : emb_q[(size_t)qts[r]*128 + e];
  }
  __syncthreads();
  // LSTM gates gi/gg/go, K=128 (h part); emb_r part from ER2 table.
  gemmKS<128,132>(WIHT,       512, XC, BIH,       XA, PB);
  __syncthreads();
  for (int f = tid; f < 2048; f += 512) {
    int r = f >> 7, e = f & 127, i = r*132 + e;
    XA[i] += PB[i] + ER2[rts[r]*512 + e];
  }
  __syncthreads();
  gemmKS<128,132>(WIHT + 256, 512, XC, BIH + 256, XB, PB);
  __syncthreads();
  for (int f = tid; f < 2048; f += 512) {
    int r = f >> 7, e = f & 127, i = r*132 + e;
    XB[i] += PB[i] + ER2[rts[r]*512 + 256 + e];
  }
  __syncthreads();
  gemmKS<128,132>(WIHT + 384, 512, XC, BIH + 384, M1, PB);
  __syncthreads();
  for (int f = tid; f < 2048; f += 512) {
    int r = f >> 7, e = f & 127, i = r*132 + e;
    float gi = XA[i], gg = XB[i];
    float go = M1[i] + PB[i] + ER2[rts[r]*512 + 384 + e];
    float h = fsig(go) * ftanh(fsig(gi) * ftanh(gg));
    XC[i] = h;
    Hfull[(size_t)(blk*16 + r)*128 + e] = h;
  }
  __syncthreads();
  gemmKS<128,132>(WQT, 128, XC, b_query, XA, PB);     // c pre-act
  __syncthreads();
  {
    const int et = tid & 31, rr = tid >> 5;   // 16 rows exactly
    float4 wv = ld4(w_W + 128 + et*4);
    float4 o = ld4(XA + rr*132 + et*4);
    float4 p = ld4(PB + rr*132 + et*4);
    float s = ftanh(o.x+p.x)*wv.x + ftanh(o.y+p.y)*wv.y
            + ftanh(o.z+p.z)*wv.z + ftanh(o.w+p.w)*wv.w;
    #pragma unroll
    for (int off = 16; off > 0; off >>= 1) s += __shfl_down(s, off);
    if (et == 0) Cq[blk*16 + rr] = s;
  }
  // ---- fused k_match: wave w handles rows w and w+8 ----
  {
    const int wv = tid >> 6;      // wave 0..7
    const int ln = tid & 63;      // lane 0..63
    for (int rr = wv; rr < 16; rr += 8) {
      int rid = blk*16 + rr;
      int b = rid / 127, t = rid - b*127;
      int q_next = question[b*SEQ + t + 1];
      int qrv = 0;
      if (ln < 40)
        qrv = s_neighbors[(size_t)q_neighbors[(size_t)q_next*4 + ln/10]*10 + ln%10];
      int q0 = question[b*SEQ + ln];
      int q1 = question[b*SEQ + 64 + ln];
      bool p0 = false, p1 = false;
      #pragma unroll 8
      for (int i = 0; i < 40; ++i) {
        int qv = __shfl(qrv, i);
        p0 |= (q0 == qv); p1 |= (q1 == qv);
      }
      p0 &= (ln < t);
      p1 &= (64 + ln < t);
      unsigned long long w0 = __ballot(p0);
      unsigned long long w1 = __ballot(p1);
      if (ln == 0) {
        size_t bt = (size_t)b*NSTEP + t;
        mwords[bt*2 + 0] = w0;
        mwords[bt*2 + 1] = w1;
        int ns = __popcll(w0) + __popcll(w1);
        nsel[bt] = ns;
        atomicMax(&Pmaxi[t], ns);
      }
    }
  }
}

__device__ __forceinline__ float wredsum(float v) {
  #pragma unroll
  for (int o = 32; o > 0; o >>= 1) v += __shfl_down(v, o);
  return v;
}
__device__ __forceinline__ float wredmax(float v) {
  #pragma unroll
  for (int o = 32; o > 0; o >>= 1) v = fmaxf(v, __shfl_down(v, o));
  return v;
}

// ---------------------------------------------------------------------------
// k_attn: collapsed attention (a[q] cancels across the softmax), y -> out
// ---------------------------------------------------------------------------
__global__ __launch_bounds__(128) void k_attn(
    const int* __restrict__ question, const float* __restrict__ qs_table,
    const float* __restrict__ emb_q, const float* __restrict__ emb_s,
    const float* __restrict__ CPAD,
    const float* __restrict__ Hfull, const float* __restrict__ Cq,
    const int* __restrict__ nsel, const unsigned long long* __restrict__ mwords,
    const int* __restrict__ Pmaxi, float* __restrict__ out)
{
  __shared__ float us[128];
  __shared__ int cols[8];
  __shared__ int cnt;
  __shared__ float smx[2];
  __shared__ float s3[2][3];
  const int tid = threadIdx.x;
  const int wid = tid >> 6;
  const int bid = blockIdx.x;
  const int b = bid / NSTEP, t = bid % NSTEP;
  const size_t bt = (size_t)b*NSTEP + t;
  const int q_next = question[b*SEQ + t + 1];

  if (tid == 0) cnt = 0;
  __syncthreads();
  {
    float4 v = ld4(qs_table + (size_t)q_next*NS + tid*4);
    if (v.x > 0.f) { int p = atomicAdd(&cnt, 1); if (p < 8) cols[p] = tid*4; }
    if (v.y > 0.f) { int p = atomicAdd(&cnt, 1); if (p < 8) cols[p] = tid*4+1; }
    if (v.z > 0.f) { int p = atomicAdd(&cnt, 1); if (p < 8) cols[p] = tid*4+2; }
    if (v.w > 0.f) { int p = atomicAdd(&cnt, 1); if (p < 8) cols[p] = tid*4+3; }
  }
  __syncthreads();
  const int nc = min(cnt, 4);
  {
    float ue = emb_q[(size_t)q_next*EMB + tid];
    for (int i = 0; i < nc; ++i) ue += emb_s[(size_t)cols[i]*EMB + tid];
    us[tid] = ue;
  }
  const float c_pad = CPAD[0];
  const float P = (float)(Pmaxi[t] - nsel[bt]);

  const unsigned long long w0 = mwords[bt*2 + 0];
  const unsigned long long w1 = mwords[bt*2 + 1];
  const bool matched = (tid < 64) ? ((w0 >> tid) & 1ull)
                                  : ((w1 >> (tid - 64)) & 1ull);
  const float c_cur = Cq[bt];
  float Cp = matched ? ((tid == 0) ? c_pad : Cq[(size_t)b*NSTEP + tid]) : -3.0e38f;
  float mh = wredmax(Cp);
  if ((tid & 63) == 0) smx[wid] = mh;
  __syncthreads();   // also publishes us[]
  float M = fmaxf(fmaxf(smx[0], smx[1]), fmaxf(c_cur, c_pad));
  float wgt = matched ? __expf(Cp - M) : 0.f;
  float dotp = 0.f;
  if (matched && tid >= 1) {  // p=0 history row is zeros
    const float* hp = Hfull + ((size_t)b*NSTEP + tid)*EMB;
    float s = 0.f;
    #pragma unroll 8
    for (int e = 0; e < 128; e += 4) {
      float4 h4 = ld4(hp + e);
      s = fmaf(us[e],h4.x, fmaf(us[e+1],h4.y, fmaf(us[e+2],h4.z, fmaf(us[e+3],h4.w, s))));
    }
    dotp = s;
  }
  float gcp = us[tid] * Hfull[bt*EMB + tid];
  float a0 = wredsum(wgt);
  float a1 = wredsum(wgt * dotp);
  float a2 = wredsum(gcp);
  if ((tid & 63) == 0) { s3[wid][0] = a0; s3[wid][1] = a1; s3[wid][2] = a2; }
  __syncthreads();
  if (tid == 0) {
    float Sexp = s3[0][0] + s3[1][0];
    float Snum = s3[0][1] + s3[1][1];
    float gc   = s3[0][2] + s3[1][2];
    float Ec = __expf(c_cur - M), Ep = __expf(c_pad - M);
    float D = Sexp + Ec + P * Ep;
    float numt = Snum + Ec * gc;
    out[b*SEQ + t + 1] = fsig(numt / D);
    if (t == 0) out[b*SEQ] = 0.5f;
  }
}

extern "C" void kernel_launch(void* const* d_in, const int* in_sizes, int n_in,
                              void* d_out, int out_size, void* d_ws, size_t ws_size,
                              hipStream_t stream) {
  const int* question    = (const int*)d_in[0];
  const int* response    = (const int*)d_in[1];
  const int* maskp       = (const int*)d_in[2];
  const int* q_neighbors = (const int*)d_in[3];
  const int* s_neighbors = (const int*)d_in[4];
  const float* qs_table  = (const float*)d_in[5];
  const float* emb_q     = (const float*)d_in[6];
  const float* emb_s     = (const float*)d_in[7];
  const float* emb_r     = (const float*)d_in[8];
  const float* W_ih      = (const float*)d_in[9];
  const float* b_ih      = (const float*)d_in[10];
  const float* b_hh      = (const float*)d_in[11];
  const float* W_agg     = (const float*)d_in[12];
  const float* b_agg     = (const float*)d_in[13];
  const float* W_last    = (const float*)d_in[14];
  const float* b_last    = (const float*)d_in[15];
  const float* W_query   = (const float*)d_in[16];
  const float* b_query   = (const float*)d_in[17];
  // d_in[18] W_key, d_in[19] b_key, d_in[21] b_W: no effect (a[q] cancels)
  const float* w_W       = (const float*)d_in[20];
  float* out = (float*)d_out;

  float* ws = (float*)d_ws;
  float* WT012 = ws;                    // 49152
  float* WLT   = ws + 49152;            // 16384
  float* WQT   = ws + 65536;            // 16384
  float* WIHT  = ws + 81920;            // 65536  [128][512] (h-half only)
  float* ER2   = ws + 147456;           // 1024   [2][512]
  float* BIH   = ws + 212992;           // 512
  float* CPAD  = ws + 213504;           // 16
  float* E1    = ws + 213520;           // 65536
  float* G1    = ws + 279056;           // 65536
  float* E2    = ws + 344592;           // 65536
  float* Hfull = ws + 410128;           // 520192
  float* Cq    = ws + 930320;           // 4064
  int*   Pmaxi = (int*)(ws + 934384);   // 128
  int*   nselp = (int*)(ws + 934512);   // 4064
  unsigned long long* mwords =
      (unsigned long long*)(((uintptr_t)(ws + 938576) + 15) & ~(uintptr_t)15);

  k_T<<<dim3(512), dim3(256), 0, stream>>>(
      W_agg, W_last, W_query, W_ih, b_ih, b_hh, b_query, w_W, emb_r,
      WT012, WLT, WQT, WIHT, ER2, BIH, CPAD, G1, Pmaxi);
  k_pre<<<dim3(352), dim3(512), 0, stream>>>(
      s_neighbors, q_neighbors, emb_q, emb_s, WT012, b_agg, E1, G1);
  k_pre2<<<dim3(32), dim3(512), 0, stream>>>(E1, G1, WT012, b_agg, E2);
  k_chain<<<dim3(254), dim3(512), 0, stream>>>(
      question, response, maskp, q_neighbors, s_neighbors, emb_q, emb_s,
      WT012, WLT, WQT, WIHT, ER2, BIH, b_agg, b_last, b_query, w_W,
      E1, E2, Hfull, Cq, nselp, mwords, Pmaxi);
  k_attn<<<dim3(NB*NSTEP), dim3(128), 0, stream>>>(
      question, qs_table, emb_q, emb_s, CPAD, Hfull, Cq,
      nselp, mwords, Pmaxi, out);
}